// Round 1
// baseline (1004.594 us; speedup 1.0000x reference)
//
#include <hip/hip_runtime.h>
#include <cstdint>
#include <cstddef>

#define FIN 512
#define FOUT 256
#define LRELU 0.2f

// ---------------- K1: seq_fts = x @ W  (f32, 64x64 tile, BK=16) ----------------
__global__ __launch_bounds__(256) void gemm_f32(
    const float* __restrict__ A,   // [M, 512]
    const float* __restrict__ B,   // [512, 256]
    float* __restrict__ C,         // [M, 256]
    int M)
{
    __shared__ float As[16][65];   // padded: scalar writes/reads
    __shared__ float Bs[16][64];   // float4 aligned, 2-way b128 (free)
    const int t  = threadIdx.x;
    const int bm = blockIdx.x * 64;
    const int bn = blockIdx.y * 64;
    const int tx = t & 15, ty = t >> 4;
    const int arow = t >> 2, ak4 = (t & 3) << 2;   // A-load: 64 rows x 16k
    const int brow = t >> 4, bcol = (t & 15) << 2; // B-load: 16 rows x 64n
    const int gr = bm + arow;
    float acc[4][4] = {};

    for (int k0 = 0; k0 < FIN; k0 += 16) {
        float4 av = make_float4(0.f, 0.f, 0.f, 0.f);
        if (gr < M) av = *(const float4*)(A + (size_t)gr * FIN + k0 + ak4);
        float4 bv = *(const float4*)(B + (size_t)(k0 + brow) * FOUT + bn + bcol);
        As[ak4 + 0][arow] = av.x;
        As[ak4 + 1][arow] = av.y;
        As[ak4 + 2][arow] = av.z;
        As[ak4 + 3][arow] = av.w;
        *(float4*)(&Bs[brow][bcol]) = bv;
        __syncthreads();
#pragma unroll
        for (int k = 0; k < 16; ++k) {
            const float a0 = As[k][ty * 4 + 0];
            const float a1 = As[k][ty * 4 + 1];
            const float a2 = As[k][ty * 4 + 2];
            const float a3 = As[k][ty * 4 + 3];
            const float4 b4 = *(const float4*)(&Bs[k][tx * 4]);
            acc[0][0] += a0 * b4.x; acc[0][1] += a0 * b4.y; acc[0][2] += a0 * b4.z; acc[0][3] += a0 * b4.w;
            acc[1][0] += a1 * b4.x; acc[1][1] += a1 * b4.y; acc[1][2] += a1 * b4.z; acc[1][3] += a1 * b4.w;
            acc[2][0] += a2 * b4.x; acc[2][1] += a2 * b4.y; acc[2][2] += a2 * b4.z; acc[2][3] += a2 * b4.w;
            acc[3][0] += a3 * b4.x; acc[3][1] += a3 * b4.y; acc[3][2] += a3 * b4.z; acc[3][3] += a3 * b4.w;
        }
        __syncthreads();
    }
#pragma unroll
    for (int i = 0; i < 4; ++i) {
        const int r = bm + ty * 4 + i;
        if (r < M) {
            float4 o = make_float4(acc[i][0], acc[i][1], acc[i][2], acc[i][3]);
            *(float4*)(C + (size_t)r * FOUT + bn + tx * 4) = o;
        }
    }
}

// ---------------- K2: f1 = seq@a1+b1, f2 = seq@a2+b2 (wave per row) ----------------
__global__ __launch_bounds__(256) void f1f2_kernel(
    const float* __restrict__ seq, const float* __restrict__ a1,
    const float* __restrict__ a2, const float* __restrict__ b1,
    const float* __restrict__ b2, float* __restrict__ f1,
    float* __restrict__ f2, int N)
{
    const int w = threadIdx.x >> 6, lane = threadIdx.x & 63;
    const int row = blockIdx.x * 4 + w;
    if (row >= N) return;
    const float4 sv  = *(const float4*)(seq + (size_t)row * FOUT + lane * 4);
    const float4 a1v = *(const float4*)(a1 + lane * 4);
    const float4 a2v = *(const float4*)(a2 + lane * 4);
    float s1 = sv.x * a1v.x + sv.y * a1v.y + sv.z * a1v.z + sv.w * a1v.w;
    float s2 = sv.x * a2v.x + sv.y * a2v.y + sv.z * a2v.z + sv.w * a2v.w;
#pragma unroll
    for (int off = 32; off; off >>= 1) {
        s1 += __shfl_xor(s1, off);
        s2 += __shfl_xor(s2, off);
    }
    if (lane == 0) {
        f1[row] = s1 + b1[0];
        f2[row] = s2 + b2[0];
    }
}

// ---------------- K3: histogram of src ----------------
__global__ void hist_kernel(const int* __restrict__ src, int* __restrict__ cnt, int E)
{
    const int i = blockIdx.x * blockDim.x + threadIdx.x;
    if (i < E) atomicAdd(&cnt[src[i]], 1);
}

// ---------------- K4: exclusive scan -> row offsets (single block) ----------------
__global__ __launch_bounds__(1024) void scan_kernel(
    const int* __restrict__ cnt, int* __restrict__ row_off, int N)
{
    __shared__ int s[1024];
    const int t = threadIdx.x;
    const int C = (N + 1023) / 1024;
    const int base = t * C;
    int sum = 0;
    for (int i = 0; i < C; ++i) {
        const int idx = base + i;
        if (idx < N) sum += cnt[idx];
    }
    s[t] = sum;
    __syncthreads();
    for (int off = 1; off < 1024; off <<= 1) {
        const int v = (t >= off) ? s[t - off] : 0;
        __syncthreads();
        s[t] += v;
        __syncthreads();
    }
    int run = (t == 0) ? 0 : s[t - 1];
    for (int i = 0; i < C; ++i) {
        const int idx = base + i;
        if (idx < N) {
            row_off[idx] = run;
            run += cnt[idx];
        }
    }
    if (t == 1023) row_off[N] = s[1023];
}

// ---------------- K5: scatter edge ids into CSR order ----------------
__global__ void scatter_kernel(const int* __restrict__ src,
                               const int* __restrict__ row_off,
                               int* __restrict__ cursor,
                               int* __restrict__ eids, int E)
{
    const int i = blockIdx.x * blockDim.x + threadIdx.x;
    if (i < E) {
        const int s = src[i];
        const int pos = row_off[s] + atomicAdd(&cursor[s], 1);
        eids[pos] = i;
    }
}

// ---------------- K6: fused per-row softmax + SPMM + bias + ELU ----------------
__global__ __launch_bounds__(256) void row_kernel(
    const float* __restrict__ seq, const float* __restrict__ f1,
    const float* __restrict__ f2, const float* __restrict__ values,
    const int* __restrict__ dst, const int* __restrict__ row_off,
    const int* __restrict__ eids, const float* __restrict__ b_out,
    float* __restrict__ out, int N)
{
    const int w = threadIdx.x >> 6, lane = threadIdx.x & 63;
    const int row = blockIdx.x * 4 + w;
    if (row >= N) return;
    const int start = row_off[row], end = row_off[row + 1];
    const float f1i = f1[row];

    // pass 1: wave-parallel max of leaky_relu(values*(f1_i + f2_j))
    float m = -INFINITY;
    for (int t = start + lane; t < end; t += 64) {
        const int e = eids[t];
        float lg = values[e] * (f1i + f2[dst[e]]);
        lg = (lg > 0.f) ? lg : LRELU * lg;
        m = fmaxf(m, lg);
    }
#pragma unroll
    for (int off = 32; off; off >>= 1) m = fmaxf(m, __shfl_xor(m, off));

    // pass 2: serial edges, lanes hold 256-wide accumulator (float4/lane)
    float4 acc = make_float4(0.f, 0.f, 0.f, 0.f);
    float denom = 0.f;
    for (int t = start; t < end; ++t) {
        const int e = eids[t];       // broadcast loads (same addr all lanes)
        const int d = dst[e];
        float lg = values[e] * (f1i + f2[d]);
        lg = (lg > 0.f) ? lg : LRELU * lg;
        const float p = __expf(lg - m);
        denom += p;
        const float4 sv = *(const float4*)(seq + (size_t)d * FOUT + lane * 4);
        acc.x += p * sv.x; acc.y += p * sv.y; acc.z += p * sv.z; acc.w += p * sv.w;
    }
    const float inv = (end > start) ? 1.f / denom : 0.f;
    const float4 bo = *(const float4*)(b_out + lane * 4);
    float4 o;
    o.x = acc.x * inv + bo.x;
    o.y = acc.y * inv + bo.y;
    o.z = acc.z * inv + bo.z;
    o.w = acc.w * inv + bo.w;
    o.x = (o.x > 0.f) ? o.x : expm1f(o.x);
    o.y = (o.y > 0.f) ? o.y : expm1f(o.y);
    o.z = (o.z > 0.f) ? o.z : expm1f(o.z);
    o.w = (o.w > 0.f) ? o.w : expm1f(o.w);
    *(float4*)(out + (size_t)row * FOUT + lane * 4) = o;
}

extern "C" void kernel_launch(void* const* d_in, const int* in_sizes, int n_in,
                              void* d_out, int out_size, void* d_ws, size_t ws_size,
                              hipStream_t stream)
{
    const float* x      = (const float*)d_in[0];
    const float* values = (const float*)d_in[1];
    const int*   ei     = (const int*)d_in[2];
    const float* W      = (const float*)d_in[3];
    const float* a1     = (const float*)d_in[4];
    const float* b1     = (const float*)d_in[5];
    const float* a2     = (const float*)d_in[6];
    const float* b2     = (const float*)d_in[7];
    const float* b_out  = (const float*)d_in[8];
    float* out = (float*)d_out;

    const int N = in_sizes[0] / FIN;   // 63001
    const int E = in_sizes[1];         // 2,000,000
    const int* src = ei;
    const int* dst = ei + E;

    // workspace layout (256B-aligned chunks)
    auto alignup = [](size_t v) { return (v + 255) & ~(size_t)255; };
    char* ws = (char*)d_ws;
    size_t off = 0;
    float* seq    = (float*)(ws + off); off = alignup(off + (size_t)N * FOUT * 4);
    float* f1     = (float*)(ws + off); off = alignup(off + (size_t)N * 4);
    float* f2     = (float*)(ws + off); off = alignup(off + (size_t)N * 4);
    int*   cnt    = (int*)(ws + off);   off = alignup(off + (size_t)N * 4);
    int*   rowoff = (int*)(ws + off);   off = alignup(off + (size_t)(N + 1) * 4);
    int*   cursor = (int*)(ws + off);   off = alignup(off + (size_t)N * 4);
    int*   eids   = (int*)(ws + off);   off = alignup(off + (size_t)E * 4);
    (void)ws_size;

    hipMemsetAsync(cnt, 0, (size_t)N * 4, stream);
    hipMemsetAsync(cursor, 0, (size_t)N * 4, stream);

    dim3 ggrid((N + 63) / 64, FOUT / 64);
    gemm_f32<<<ggrid, 256, 0, stream>>>(x, W, seq, N);

    f1f2_kernel<<<(N + 3) / 4, 256, 0, stream>>>(seq, a1, a2, b1, b2, f1, f2, N);

    hist_kernel<<<(E + 255) / 256, 256, 0, stream>>>(src, cnt, E);

    scan_kernel<<<1, 1024, 0, stream>>>(cnt, rowoff, N);

    scatter_kernel<<<(E + 255) / 256, 256, 0, stream>>>(src, rowoff, cursor, eids, E);

    row_kernel<<<(N + 3) / 4, 256, 0, stream>>>(seq, f1, f2, values, dst, rowoff,
                                                eids, b_out, out, N);
}

// Round 2
// 665.382 us; speedup vs baseline: 1.5098x; 1.5098x over previous
//
#include <hip/hip_runtime.h>
#include <cstdint>
#include <cstddef>

#define FIN 512
#define FOUT 256
#define LRELU 0.2f

typedef __attribute__((ext_vector_type(8))) short bf16x8;
typedef __attribute__((ext_vector_type(8))) unsigned short u16x8;
typedef __attribute__((ext_vector_type(4))) float f32x4;

__device__ inline ushort f2bf(float f) {
    union { float f; uint32_t u; } c; c.f = f;
    uint32_t u = c.u;
    return (ushort)((u + 0x7FFF + ((u >> 16) & 1)) >> 16);   // RNE
}
__device__ inline float bf2f(ushort h) {
    union { uint32_t u; float f; } c; c.u = ((uint32_t)h) << 16;
    return c.f;
}

// ---------------- K0: WT_bf[n][k] = bf16(W[k][n]) ----------------
__global__ void prep_wt(const float* __restrict__ W, ushort* __restrict__ WT)
{
    const int idx = blockIdx.x * blockDim.x + threadIdx.x;   // 512*256
    if (idx < FIN * FOUT) {
        const int k = idx >> 8, n = idx & 255;
        WT[(size_t)n * FIN + k] = f2bf(W[(size_t)k * FOUT + n]);
    }
}

// ---------------- K1: seq_bf = bf16(x @ W)  (MFMA bf16, 64x256 tile) ----------------
#define BM 64
#define BK 64
__global__ __launch_bounds__(256) void gemm_bf16(
    const float* __restrict__ A,      // [M,512] f32
    const ushort* __restrict__ BT,    // [256,512] bf16, n-major
    ushort* __restrict__ Cbf,         // [M,256] bf16
    int M)
{
    __shared__ ushort As[BM * BK];    // [row][k], 16B-chunk XOR swizzle
    __shared__ ushort Bs[FOUT * BK];  // [col][k], same swizzle
    const int t = threadIdx.x;
    const int lane = t & 63, w = t >> 6;
    const int wm = w & 1, wn = w >> 1;          // wave -> 32-row x 128-col subtile
    const int brow = blockIdx.x * BM;

    f32x4 acc[2][8] = {};

    const int ar = t >> 2;            // A-stage row 0..63
    const int ak = (t & 3) << 4;      // A-stage k base {0,16,32,48}

    for (int k0 = 0; k0 < FIN; k0 += BK) {
        // ---- stage A tile (f32 -> bf16, swizzled) ----
        {
            float4 v0, v1, v2, v3;
            const int grow = brow + ar;
            if (grow < M) {
                const float* p = A + (size_t)grow * FIN + k0 + ak;
                v0 = ((const float4*)p)[0]; v1 = ((const float4*)p)[1];
                v2 = ((const float4*)p)[2]; v3 = ((const float4*)p)[3];
            } else {
                v0 = v1 = v2 = v3 = make_float4(0.f, 0.f, 0.f, 0.f);
            }
            u16x8 w0, w1;
            const float* vf = (const float*)&v0;   // v0..v3 contiguous? not guaranteed; do explicitly
            w0[0]=f2bf(v0.x); w0[1]=f2bf(v0.y); w0[2]=f2bf(v0.z); w0[3]=f2bf(v0.w);
            w0[4]=f2bf(v1.x); w0[5]=f2bf(v1.y); w0[6]=f2bf(v1.z); w0[7]=f2bf(v1.w);
            w1[0]=f2bf(v2.x); w1[1]=f2bf(v2.y); w1[2]=f2bf(v2.z); w1[3]=f2bf(v2.w);
            w1[4]=f2bf(v3.x); w1[5]=f2bf(v3.y); w1[6]=f2bf(v3.z); w1[7]=f2bf(v3.w);
            (void)vf;
            const int c0 = ((ak >> 3) + 0) ^ (ar & 7);
            const int c1 = ((ak >> 3) + 1) ^ (ar & 7);
            *(u16x8*)(&As[ar * BK + (c0 << 3)]) = w0;
            *(u16x8*)(&As[ar * BK + (c1 << 3)]) = w1;
        }
        // ---- stage B tile (bf16 copy, swizzled); thread t = col n ----
        {
            const ushort* bp = BT + (size_t)t * FIN + k0;
#pragma unroll
            for (int c = 0; c < 8; ++c) {
                u16x8 bv = *(const u16x8*)(bp + (c << 3));
                *(u16x8*)(&Bs[t * BK + ((c ^ (t & 7)) << 3)]) = bv;
            }
        }
        __syncthreads();

#pragma unroll
        for (int kk = 0; kk < 2; ++kk) {
            const int kc = kk * 4 + (lane >> 4);       // 16B chunk index along k
            bf16x8 af[2], bfr[8];
#pragma unroll
            for (int m = 0; m < 2; ++m) {
                const int row = wm * 32 + m * 16 + (lane & 15);
                af[m] = *(const bf16x8*)(&As[row * BK + ((kc ^ (row & 7)) << 3)]);
            }
#pragma unroll
            for (int n = 0; n < 8; ++n) {
                const int col = wn * 128 + n * 16 + (lane & 15);
                bfr[n] = *(const bf16x8*)(&Bs[col * BK + ((kc ^ (col & 7)) << 3)]);
            }
#pragma unroll
            for (int m = 0; m < 2; ++m)
#pragma unroll
                for (int n = 0; n < 8; ++n)
                    acc[m][n] = __builtin_amdgcn_mfma_f32_16x16x32_bf16(
                        af[m], bfr[n], acc[m][n], 0, 0, 0);
        }
        __syncthreads();
    }

    // ---- epilogue: C/D layout col=lane&15, row=(lane>>4)*4+reg ----
    const int cbase = wn * 128 + (lane & 15);
#pragma unroll
    for (int m = 0; m < 2; ++m) {
#pragma unroll
        for (int reg = 0; reg < 4; ++reg) {
            const int r = brow + wm * 32 + m * 16 + (lane >> 4) * 4 + reg;
            if (r < M) {
#pragma unroll
                for (int n = 0; n < 8; ++n) {
                    Cbf[(size_t)r * FOUT + cbase + n * 16] = f2bf(acc[m][n][reg]);
                }
            }
        }
    }
}

// ---------------- K2: f1,f2 from bf16 seq (wave per row) ----------------
__global__ __launch_bounds__(256) void f1f2_kernel(
    const ushort* __restrict__ seq, const float* __restrict__ a1,
    const float* __restrict__ a2, const float* __restrict__ b1,
    const float* __restrict__ b2, float* __restrict__ f1,
    float* __restrict__ f2, int N)
{
    const int w = threadIdx.x >> 6, lane = threadIdx.x & 63;
    const int row = blockIdx.x * 4 + w;
    if (row >= N) return;
    const ushort4 sv = ((const ushort4*)(seq + (size_t)row * FOUT))[lane];
    const float4 a1v = *(const float4*)(a1 + lane * 4);
    const float4 a2v = *(const float4*)(a2 + lane * 4);
    const float s0 = bf2f(sv.x), s1v = bf2f(sv.y), s2v = bf2f(sv.z), s3 = bf2f(sv.w);
    float s1 = s0 * a1v.x + s1v * a1v.y + s2v * a1v.z + s3 * a1v.w;
    float s2 = s0 * a2v.x + s1v * a2v.y + s2v * a2v.z + s3 * a2v.w;
#pragma unroll
    for (int off = 32; off; off >>= 1) {
        s1 += __shfl_xor(s1, off);
        s2 += __shfl_xor(s2, off);
    }
    if (lane == 0) {
        f1[row] = s1 + b1[0];
        f2[row] = s2 + b2[0];
    }
}

// ---------------- K3: histogram of src ----------------
__global__ void hist_kernel(const int* __restrict__ src, int* __restrict__ cnt, int E)
{
    const int i = blockIdx.x * blockDim.x + threadIdx.x;
    if (i < E) atomicAdd(&cnt[src[i]], 1);
}

// ---------------- K4: exclusive scan -> row offsets (single block) ----------------
__global__ __launch_bounds__(1024) void scan_kernel(
    const int* __restrict__ cnt, int* __restrict__ row_off, int N)
{
    __shared__ int s[1024];
    const int t = threadIdx.x;
    const int C = (N + 1023) / 1024;
    const int base = t * C;
    int sum = 0;
    for (int i = 0; i < C; ++i) {
        const int idx = base + i;
        if (idx < N) sum += cnt[idx];
    }
    s[t] = sum;
    __syncthreads();
    for (int off = 1; off < 1024; off <<= 1) {
        const int v = (t >= off) ? s[t - off] : 0;
        __syncthreads();
        s[t] += v;
        __syncthreads();
    }
    int run = (t == 0) ? 0 : s[t - 1];
    for (int i = 0; i < C; ++i) {
        const int idx = base + i;
        if (idx < N) {
            row_off[idx] = run;
            run += cnt[idx];
        }
    }
    if (t == 1023) row_off[N] = s[1023];
}

// ---------------- K5: scatter edge ids into CSR order ----------------
__global__ void scatter_kernel(const int* __restrict__ src,
                               const int* __restrict__ row_off,
                               int* __restrict__ cursor,
                               int* __restrict__ eids, int E)
{
    const int i = blockIdx.x * blockDim.x + threadIdx.x;
    if (i < E) {
        const int s = src[i];
        const int pos = row_off[s] + atomicAdd(&cursor[s], 1);
        eids[pos] = i;
    }
}

// ---------------- K6: fused per-row softmax + SPMM + bias + ELU ----------------
__global__ __launch_bounds__(256) void row_kernel(
    const ushort* __restrict__ seq, const float* __restrict__ f1,
    const float* __restrict__ f2, const float* __restrict__ values,
    const int* __restrict__ dst, const int* __restrict__ row_off,
    const int* __restrict__ eids, const float* __restrict__ b_out,
    float* __restrict__ out, int N)
{
    const int w = threadIdx.x >> 6, lane = threadIdx.x & 63;
    const int row = blockIdx.x * 4 + w;
    if (row >= N) return;
    const int start = row_off[row], end = row_off[row + 1];
    const float f1i = f1[row];

    // pass 1: wave-parallel max of leaky_relu(values*(f1_i + f2_j))
    float m = -INFINITY;
    for (int t = start + lane; t < end; t += 64) {
        const int e = eids[t];
        float lg = values[e] * (f1i + f2[dst[e]]);
        lg = (lg > 0.f) ? lg : LRELU * lg;
        m = fmaxf(m, lg);
    }
#pragma unroll
    for (int off = 32; off; off >>= 1) m = fmaxf(m, __shfl_xor(m, off));

    // pass 2: serial edges (x2 unrolled, independent chains), bf16 gather
    float4 accA = make_float4(0.f, 0.f, 0.f, 0.f);
    float4 accB = make_float4(0.f, 0.f, 0.f, 0.f);
    float den0 = 0.f, den1 = 0.f;
    int t = start;
    for (; t + 2 <= end; t += 2) {
        const int e0 = eids[t], e1 = eids[t + 1];
        const int d0 = dst[e0], d1 = dst[e1];
        const float v0 = values[e0], v1 = values[e1];
        float l0 = v0 * (f1i + f2[d0]); l0 = (l0 > 0.f) ? l0 : LRELU * l0;
        float l1 = v1 * (f1i + f2[d1]); l1 = (l1 > 0.f) ? l1 : LRELU * l1;
        const float p0 = __expf(l0 - m), p1 = __expf(l1 - m);
        const ushort4 s0 = ((const ushort4*)(seq + (size_t)d0 * FOUT))[lane];
        const ushort4 s1 = ((const ushort4*)(seq + (size_t)d1 * FOUT))[lane];
        den0 += p0; den1 += p1;
        accA.x += p0 * bf2f(s0.x); accA.y += p0 * bf2f(s0.y);
        accA.z += p0 * bf2f(s0.z); accA.w += p0 * bf2f(s0.w);
        accB.x += p1 * bf2f(s1.x); accB.y += p1 * bf2f(s1.y);
        accB.z += p1 * bf2f(s1.z); accB.w += p1 * bf2f(s1.w);
    }
    if (t < end) {
        const int e0 = eids[t];
        const int d0 = dst[e0];
        const float v0 = values[e0];
        float l0 = v0 * (f1i + f2[d0]); l0 = (l0 > 0.f) ? l0 : LRELU * l0;
        const float p0 = __expf(l0 - m);
        const ushort4 s0 = ((const ushort4*)(seq + (size_t)d0 * FOUT))[lane];
        den0 += p0;
        accA.x += p0 * bf2f(s0.x); accA.y += p0 * bf2f(s0.y);
        accA.z += p0 * bf2f(s0.z); accA.w += p0 * bf2f(s0.w);
    }
    const float denom = den0 + den1;
    const float inv = (end > start) ? 1.f / denom : 0.f;
    const float4 bo = *(const float4*)(b_out + lane * 4);
    float4 o;
    o.x = (accA.x + accB.x) * inv + bo.x;
    o.y = (accA.y + accB.y) * inv + bo.y;
    o.z = (accA.z + accB.z) * inv + bo.z;
    o.w = (accA.w + accB.w) * inv + bo.w;
    o.x = (o.x > 0.f) ? o.x : expm1f(o.x);
    o.y = (o.y > 0.f) ? o.y : expm1f(o.y);
    o.z = (o.z > 0.f) ? o.z : expm1f(o.z);
    o.w = (o.w > 0.f) ? o.w : expm1f(o.w);
    *(float4*)(out + (size_t)row * FOUT + lane * 4) = o;
}

extern "C" void kernel_launch(void* const* d_in, const int* in_sizes, int n_in,
                              void* d_out, int out_size, void* d_ws, size_t ws_size,
                              hipStream_t stream)
{
    const float* x      = (const float*)d_in[0];
    const float* values = (const float*)d_in[1];
    const int*   ei     = (const int*)d_in[2];
    const float* W      = (const float*)d_in[3];
    const float* a1     = (const float*)d_in[4];
    const float* b1     = (const float*)d_in[5];
    const float* a2     = (const float*)d_in[6];
    const float* b2     = (const float*)d_in[7];
    const float* b_out  = (const float*)d_in[8];
    float* out = (float*)d_out;

    const int N = in_sizes[0] / FIN;   // 63001
    const int E = in_sizes[1];         // 2,000,000
    const int* src = ei;
    const int* dst = ei + E;

    auto alignup = [](size_t v) { return (v + 255) & ~(size_t)255; };
    char* ws = (char*)d_ws;
    size_t off = 0;
    ushort* seqbf = (ushort*)(ws + off); off = alignup(off + (size_t)N * FOUT * 2);
    ushort* WT    = (ushort*)(ws + off); off = alignup(off + (size_t)FIN * FOUT * 2);
    float*  f1    = (float*)(ws + off);  off = alignup(off + (size_t)N * 4);
    float*  f2    = (float*)(ws + off);  off = alignup(off + (size_t)N * 4);
    int*    cnt   = (int*)(ws + off);    off = alignup(off + (size_t)N * 4);
    int*    rowoff= (int*)(ws + off);    off = alignup(off + (size_t)(N + 1) * 4);
    int*    cursor= (int*)(ws + off);    off = alignup(off + (size_t)N * 4);
    int*    eids  = (int*)(ws + off);    off = alignup(off + (size_t)E * 4);
    (void)ws_size;

    hipMemsetAsync(cnt, 0, (size_t)N * 4, stream);
    hipMemsetAsync(cursor, 0, (size_t)N * 4, stream);

    prep_wt<<<(FIN * FOUT + 255) / 256, 256, 0, stream>>>(W, WT);

    gemm_bf16<<<(N + BM - 1) / BM, 256, 0, stream>>>(x, WT, seqbf, N);

    f1f2_kernel<<<(N + 3) / 4, 256, 0, stream>>>(seqbf, a1, a2, b1, b2, f1, f2, N);

    hist_kernel<<<(E + 255) / 256, 256, 0, stream>>>(src, cnt, E);

    scan_kernel<<<1, 1024, 0, stream>>>(cnt, rowoff, N);

    scatter_kernel<<<(E + 255) / 256, 256, 0, stream>>>(src, rowoff, cursor, eids, E);

    row_kernel<<<(N + 3) / 4, 256, 0, stream>>>(seqbf, f1, f2, values, dst, rowoff,
                                                eids, b_out, out, N);
}

// Round 3
// 509.624 us; speedup vs baseline: 1.9712x; 1.3056x over previous
//
#include <hip/hip_runtime.h>
#include <cstdint>
#include <cstddef>

#define FIN 512
#define FOUT 256
#define LRELU 0.2f

typedef __attribute__((ext_vector_type(8))) short bf16x8;
typedef __attribute__((ext_vector_type(8))) unsigned short u16x8;
typedef __attribute__((ext_vector_type(4))) float f32x4;

__device__ inline ushort f2bf(float f) {
    union { float f; uint32_t u; } c; c.f = f;
    uint32_t u = c.u;
    return (ushort)((u + 0x7FFF + ((u >> 16) & 1)) >> 16);   // RNE
}
__device__ inline float bf2f(ushort h) {
    union { uint32_t u; float f; } c; c.u = ((uint32_t)h) << 16;
    return c.f;
}

// ---------------- K0: WT_bf[n][k] = bf16(W[k][n]) ----------------
__global__ void prep_wt(const float* __restrict__ W, ushort* __restrict__ WT)
{
    const int idx = blockIdx.x * blockDim.x + threadIdx.x;   // 512*256
    if (idx < FIN * FOUT) {
        const int k = idx >> 8, n = idx & 255;
        WT[(size_t)n * FIN + k] = f2bf(W[(size_t)k * FOUT + n]);
    }
}

// ---------------- K1: seq_bf = bf16(x @ W)  (MFMA bf16, 128x256 tile) ----------------
#define BM 128
#define BK 64
__global__ __launch_bounds__(512) void gemm_bf16(
    const float* __restrict__ A,      // [M,512] f32
    const ushort* __restrict__ BT,    // [256,512] bf16, n-major
    ushort* __restrict__ Cbf,         // [M,256] bf16
    int M)
{
    __shared__ ushort As[BM * BK];    // [row][k], 16B-chunk XOR swizzle -> 16 KB
    __shared__ ushort Bs[FOUT * BK];  // [col][k], same swizzle -> 32 KB
    const int t = threadIdx.x;
    const int lane = t & 63, w = t >> 6;
    const int wm = w & 3, wn = w >> 2;          // 8 waves: 4 row-groups x 2 col-groups
    const int brow = blockIdx.x * BM;

    f32x4 acc[2][8] = {};

    const int ar = t >> 2;            // A-stage row 0..127
    const int ak = (t & 3) << 4;      // A-stage k base {0,16,32,48}
    const int bcol = t >> 1;          // B-stage col 0..255
    const int bkc = (t & 1) * 4;      // B-stage chunk base {0,4}

    for (int k0 = 0; k0 < FIN; k0 += BK) {
        // ---- stage A tile (f32 -> bf16, swizzled) ----
        {
            float4 v0, v1, v2, v3;
            const int grow = brow + ar;
            if (grow < M) {
                const float* p = A + (size_t)grow * FIN + k0 + ak;
                v0 = ((const float4*)p)[0]; v1 = ((const float4*)p)[1];
                v2 = ((const float4*)p)[2]; v3 = ((const float4*)p)[3];
            } else {
                v0 = v1 = v2 = v3 = make_float4(0.f, 0.f, 0.f, 0.f);
            }
            u16x8 w0, w1;
            w0[0]=f2bf(v0.x); w0[1]=f2bf(v0.y); w0[2]=f2bf(v0.z); w0[3]=f2bf(v0.w);
            w0[4]=f2bf(v1.x); w0[5]=f2bf(v1.y); w0[6]=f2bf(v1.z); w0[7]=f2bf(v1.w);
            w1[0]=f2bf(v2.x); w1[1]=f2bf(v2.y); w1[2]=f2bf(v2.z); w1[3]=f2bf(v2.w);
            w1[4]=f2bf(v3.x); w1[5]=f2bf(v3.y); w1[6]=f2bf(v3.z); w1[7]=f2bf(v3.w);
            const int c0 = ((ak >> 3) + 0) ^ (ar & 7);
            const int c1 = ((ak >> 3) + 1) ^ (ar & 7);
            *(u16x8*)(&As[ar * BK + (c0 << 3)]) = w0;
            *(u16x8*)(&As[ar * BK + (c1 << 3)]) = w1;
        }
        // ---- stage B tile (bf16 copy, swizzled); 2 threads per col ----
        {
            const ushort* bp = BT + (size_t)bcol * FIN + k0;
#pragma unroll
            for (int j = 0; j < 4; ++j) {
                const int c = bkc + j;
                u16x8 bv = *(const u16x8*)(bp + (c << 3));
                *(u16x8*)(&Bs[bcol * BK + ((c ^ (bcol & 7)) << 3)]) = bv;
            }
        }
        __syncthreads();

#pragma unroll
        for (int kk = 0; kk < 2; ++kk) {
            const int kc = kk * 4 + (lane >> 4);       // 16B chunk index along k
            bf16x8 af[2], bfr[8];
#pragma unroll
            for (int m = 0; m < 2; ++m) {
                const int row = wm * 32 + m * 16 + (lane & 15);
                af[m] = *(const bf16x8*)(&As[row * BK + ((kc ^ (row & 7)) << 3)]);
            }
#pragma unroll
            for (int n = 0; n < 8; ++n) {
                const int col = wn * 128 + n * 16 + (lane & 15);
                bfr[n] = *(const bf16x8*)(&Bs[col * BK + ((kc ^ (col & 7)) << 3)]);
            }
#pragma unroll
            for (int m = 0; m < 2; ++m)
#pragma unroll
                for (int n = 0; n < 8; ++n)
                    acc[m][n] = __builtin_amdgcn_mfma_f32_16x16x32_bf16(
                        af[m], bfr[n], acc[m][n], 0, 0, 0);
        }
        __syncthreads();
    }

    // ---- epilogue: C/D layout col=lane&15, row=(lane>>4)*4+reg ----
    const int cbase = wn * 128 + (lane & 15);
#pragma unroll
    for (int m = 0; m < 2; ++m) {
#pragma unroll
        for (int reg = 0; reg < 4; ++reg) {
            const int r = brow + wm * 32 + m * 16 + (lane >> 4) * 4 + reg;
            if (r < M) {
#pragma unroll
                for (int n = 0; n < 8; ++n) {
                    Cbf[(size_t)r * FOUT + cbase + n * 16] = f2bf(acc[m][n][reg]);
                }
            }
        }
    }
}

// ---------------- K2: f1,f2 from bf16 seq (wave per row) ----------------
__global__ __launch_bounds__(256) void f1f2_kernel(
    const ushort* __restrict__ seq, const float* __restrict__ a1,
    const float* __restrict__ a2, const float* __restrict__ b1,
    const float* __restrict__ b2, float* __restrict__ f1,
    float* __restrict__ f2, int N)
{
    const int w = threadIdx.x >> 6, lane = threadIdx.x & 63;
    const int row = blockIdx.x * 4 + w;
    if (row >= N) return;
    const ushort4 sv = ((const ushort4*)(seq + (size_t)row * FOUT))[lane];
    const float4 a1v = *(const float4*)(a1 + lane * 4);
    const float4 a2v = *(const float4*)(a2 + lane * 4);
    const float s0 = bf2f(sv.x), s1v = bf2f(sv.y), s2v = bf2f(sv.z), s3 = bf2f(sv.w);
    float s1 = s0 * a1v.x + s1v * a1v.y + s2v * a1v.z + s3 * a1v.w;
    float s2 = s0 * a2v.x + s1v * a2v.y + s2v * a2v.z + s3 * a2v.w;
#pragma unroll
    for (int off = 32; off; off >>= 1) {
        s1 += __shfl_xor(s1, off);
        s2 += __shfl_xor(s2, off);
    }
    if (lane == 0) {
        f1[row] = s1 + b1[0];
        f2[row] = s2 + b2[0];
    }
}

// ---------------- K3: histogram of src ----------------
__global__ void hist_kernel(const int* __restrict__ src, int* __restrict__ cnt, int E)
{
    const int i = blockIdx.x * blockDim.x + threadIdx.x;
    if (i < E) atomicAdd(&cnt[src[i]], 1);
}

// ---------------- K4: exclusive scan -> row offsets (single block) ----------------
__global__ __launch_bounds__(1024) void scan_kernel(
    const int* __restrict__ cnt, int* __restrict__ row_off, int N)
{
    __shared__ int s[1024];
    const int t = threadIdx.x;
    const int C = (N + 1023) / 1024;
    const int base = t * C;
    int sum = 0;
    for (int i = 0; i < C; ++i) {
        const int idx = base + i;
        if (idx < N) sum += cnt[idx];
    }
    s[t] = sum;
    __syncthreads();
    for (int off = 1; off < 1024; off <<= 1) {
        const int v = (t >= off) ? s[t - off] : 0;
        __syncthreads();
        s[t] += v;
        __syncthreads();
    }
    int run = (t == 0) ? 0 : s[t - 1];
    for (int i = 0; i < C; ++i) {
        const int idx = base + i;
        if (idx < N) {
            row_off[idx] = run;
            run += cnt[idx];
        }
    }
    if (t == 1023) row_off[N] = s[1023];
}

// ---------------- K5: scatter p=exp(leaky_relu(v*(f1+f2))) + dst into CSR ----------------
// No max-subtraction needed: values in [0,1), f1,f2 ~ N(0,1) -> |logit| <~ 10,
// exp(logit) <= e^10 ~ 2.2e4, far from f32 overflow; coefs identical in exact math.
__global__ void scatter_p(const int* __restrict__ src, const int* __restrict__ dst,
                          const float* __restrict__ values,
                          const float* __restrict__ f1, const float* __restrict__ f2,
                          const int* __restrict__ row_off, int* __restrict__ cursor,
                          float2* __restrict__ pd, int E)
{
    const int i = blockIdx.x * blockDim.x + threadIdx.x;
    if (i < E) {
        const int s = src[i];
        const int d = dst[i];
        float lg = values[i] * (f1[s] + f2[d]);
        lg = (lg > 0.f) ? lg : LRELU * lg;
        const float p = __expf(lg);
        const int pos = row_off[s] + atomicAdd(&cursor[s], 1);
        pd[pos] = make_float2(p, __int_as_float(d));
    }
}

// ---------------- K6: single-pass SPMM + normalize + bias + ELU ----------------
__global__ __launch_bounds__(256) void spmm_kernel(
    const ushort* __restrict__ seq, const float2* __restrict__ pd,
    const int* __restrict__ row_off, const float* __restrict__ b_out,
    float* __restrict__ out, int N)
{
    const int w = threadIdx.x >> 6, lane = threadIdx.x & 63;
    const int row = blockIdx.x * 4 + w;
    if (row >= N) return;
    const int start = row_off[row], end = row_off[row + 1];

    float4 a0 = make_float4(0.f,0.f,0.f,0.f), a1 = a0, a2 = a0, a3 = a0;
    float den0 = 0.f, den1 = 0.f, den2 = 0.f, den3 = 0.f;
    int t = start;
    for (; t + 4 <= end; t += 4) {
        const float2 q0 = pd[t], q1 = pd[t + 1], q2 = pd[t + 2], q3 = pd[t + 3];
        const int d0 = __float_as_int(q0.y), d1 = __float_as_int(q1.y);
        const int d2 = __float_as_int(q2.y), d3 = __float_as_int(q3.y);
        const ushort4 s0 = ((const ushort4*)(seq + (size_t)d0 * FOUT))[lane];
        const ushort4 s1 = ((const ushort4*)(seq + (size_t)d1 * FOUT))[lane];
        const ushort4 s2 = ((const ushort4*)(seq + (size_t)d2 * FOUT))[lane];
        const ushort4 s3 = ((const ushort4*)(seq + (size_t)d3 * FOUT))[lane];
        den0 += q0.x; den1 += q1.x; den2 += q2.x; den3 += q3.x;
        a0.x += q0.x * bf2f(s0.x); a0.y += q0.x * bf2f(s0.y);
        a0.z += q0.x * bf2f(s0.z); a0.w += q0.x * bf2f(s0.w);
        a1.x += q1.x * bf2f(s1.x); a1.y += q1.x * bf2f(s1.y);
        a1.z += q1.x * bf2f(s1.z); a1.w += q1.x * bf2f(s1.w);
        a2.x += q2.x * bf2f(s2.x); a2.y += q2.x * bf2f(s2.y);
        a2.z += q2.x * bf2f(s2.z); a2.w += q2.x * bf2f(s2.w);
        a3.x += q3.x * bf2f(s3.x); a3.y += q3.x * bf2f(s3.y);
        a3.z += q3.x * bf2f(s3.z); a3.w += q3.x * bf2f(s3.w);
    }
    for (; t < end; ++t) {
        const float2 q0 = pd[t];
        const int d0 = __float_as_int(q0.y);
        const ushort4 s0 = ((const ushort4*)(seq + (size_t)d0 * FOUT))[lane];
        den0 += q0.x;
        a0.x += q0.x * bf2f(s0.x); a0.y += q0.x * bf2f(s0.y);
        a0.z += q0.x * bf2f(s0.z); a0.w += q0.x * bf2f(s0.w);
    }
    const float denom = (den0 + den1) + (den2 + den3);
    const float inv = (end > start) ? 1.f / denom : 0.f;
    const float4 bo = *(const float4*)(b_out + lane * 4);
    float4 o;
    o.x = ((a0.x + a1.x) + (a2.x + a3.x)) * inv + bo.x;
    o.y = ((a0.y + a1.y) + (a2.y + a3.y)) * inv + bo.y;
    o.z = ((a0.z + a1.z) + (a2.z + a3.z)) * inv + bo.z;
    o.w = ((a0.w + a1.w) + (a2.w + a3.w)) * inv + bo.w;
    o.x = (o.x > 0.f) ? o.x : expm1f(o.x);
    o.y = (o.y > 0.f) ? o.y : expm1f(o.y);
    o.z = (o.z > 0.f) ? o.z : expm1f(o.z);
    o.w = (o.w > 0.f) ? o.w : expm1f(o.w);
    *(float4*)(out + (size_t)row * FOUT + lane * 4) = o;
}

extern "C" void kernel_launch(void* const* d_in, const int* in_sizes, int n_in,
                              void* d_out, int out_size, void* d_ws, size_t ws_size,
                              hipStream_t stream)
{
    const float* x      = (const float*)d_in[0];
    const float* values = (const float*)d_in[1];
    const int*   ei     = (const int*)d_in[2];
    const float* W      = (const float*)d_in[3];
    const float* a1     = (const float*)d_in[4];
    const float* b1     = (const float*)d_in[5];
    const float* a2     = (const float*)d_in[6];
    const float* b2     = (const float*)d_in[7];
    const float* b_out  = (const float*)d_in[8];
    float* out = (float*)d_out;

    const int N = in_sizes[0] / FIN;   // 63001
    const int E = in_sizes[1];         // 2,000,000
    const int* src = ei;
    const int* dst = ei + E;

    auto alignup = [](size_t v) { return (v + 255) & ~(size_t)255; };
    char* ws = (char*)d_ws;
    size_t off = 0;
    ushort* seqbf = (ushort*)(ws + off); off = alignup(off + (size_t)N * FOUT * 2);
    ushort* WT    = (ushort*)(ws + off); off = alignup(off + (size_t)FIN * FOUT * 2);
    float*  f1    = (float*)(ws + off);  off = alignup(off + (size_t)N * 4);
    float*  f2    = (float*)(ws + off);  off = alignup(off + (size_t)N * 4);
    int*    cnt   = (int*)(ws + off);    off = alignup(off + (size_t)N * 4);
    int*    rowoff= (int*)(ws + off);    off = alignup(off + (size_t)(N + 1) * 4);
    int*    cursor= (int*)(ws + off);    off = alignup(off + (size_t)N * 4);
    float2* pd    = (float2*)(ws + off); off = alignup(off + (size_t)E * 8);
    (void)ws_size;

    hipMemsetAsync(cnt, 0, (size_t)N * 4, stream);
    hipMemsetAsync(cursor, 0, (size_t)N * 4, stream);

    prep_wt<<<(FIN * FOUT + 255) / 256, 256, 0, stream>>>(W, WT);

    gemm_bf16<<<(N + BM - 1) / BM, 512, 0, stream>>>(x, WT, seqbf, N);

    f1f2_kernel<<<(N + 3) / 4, 256, 0, stream>>>(seqbf, a1, a2, b1, b2, f1, f2, N);

    hist_kernel<<<(E + 255) / 256, 256, 0, stream>>>(src, cnt, E);

    scan_kernel<<<1, 1024, 0, stream>>>(cnt, rowoff, N);

    scatter_p<<<(E + 255) / 256, 256, 0, stream>>>(src, dst, values, f1, f2,
                                                   rowoff, cursor, pd, E);

    spmm_kernel<<<(N + 3) / 4, 256, 0, stream>>>(seqbf, pd, rowoff, b_out, out, N);
}

// Round 4
// 391.983 us; speedup vs baseline: 2.5628x; 1.3001x over previous
//
#include <hip/hip_runtime.h>
#include <cstdint>
#include <cstddef>

#define FIN 512
#define FOUT 256
#define LRELU 0.2f

typedef __attribute__((ext_vector_type(8))) short bf16x8;
typedef __attribute__((ext_vector_type(8))) unsigned short u16x8;
typedef __attribute__((ext_vector_type(4))) float f32x4;

__device__ inline ushort f2bf(float f) {
    union { float f; uint32_t u; } c; c.f = f;
    uint32_t u = c.u;
    return (ushort)((u + 0x7FFF + ((u >> 16) & 1)) >> 16);   // RNE
}
__device__ inline float bf2f(ushort h) {
    union { uint32_t u; float f; } c; c.u = ((uint32_t)h) << 16;
    return c.f;
}

// ---------------- prep: WT_bf[n][k] = bf16(W[k][n]) ----------------
__global__ void prep_wt(const float* __restrict__ W, ushort* __restrict__ WT)
{
    const int idx = blockIdx.x * blockDim.x + threadIdx.x;   // 512*256
    if (idx < FIN * FOUT) {
        const int k = idx >> 8, n = idx & 255;
        WT[(size_t)n * FIN + k] = f2bf(W[(size_t)k * FOUT + n]);
    }
}

// ---------------- gemm: seq_bf = bf16(x @ W)  (MFMA bf16, 128x256 tile) ----------------
#define BM 128
#define BK 64
__global__ __launch_bounds__(512) void gemm_bf16(
    const float* __restrict__ A,      // [M,512] f32
    const ushort* __restrict__ BT,    // [256,512] bf16, n-major
    ushort* __restrict__ Cbf,         // [M,256] bf16
    int M)
{
    __shared__ ushort As[BM * BK];    // 16 KB, 16B-chunk XOR swizzle
    __shared__ ushort Bs[FOUT * BK];  // 32 KB
    const int t = threadIdx.x;
    const int lane = t & 63, w = t >> 6;
    const int wm = w & 3, wn = w >> 2;
    const int brow = blockIdx.x * BM;

    f32x4 acc[2][8] = {};

    const int ar = t >> 2;
    const int ak = (t & 3) << 4;
    const int bcol = t >> 1;
    const int bkc = (t & 1) * 4;

    for (int k0 = 0; k0 < FIN; k0 += BK) {
        {
            f32x4 v0, v1, v2, v3;
            const int grow = brow + ar;
            if (grow < M) {
                const f32x4* p = (const f32x4*)(A + (size_t)grow * FIN + k0 + ak);
                v0 = __builtin_nontemporal_load(p + 0);
                v1 = __builtin_nontemporal_load(p + 1);
                v2 = __builtin_nontemporal_load(p + 2);
                v3 = __builtin_nontemporal_load(p + 3);
            } else {
                v0 = v1 = v2 = v3 = (f32x4)0.f;
            }
            u16x8 w0, w1;
            w0[0]=f2bf(v0[0]); w0[1]=f2bf(v0[1]); w0[2]=f2bf(v0[2]); w0[3]=f2bf(v0[3]);
            w0[4]=f2bf(v1[0]); w0[5]=f2bf(v1[1]); w0[6]=f2bf(v1[2]); w0[7]=f2bf(v1[3]);
            w1[0]=f2bf(v2[0]); w1[1]=f2bf(v2[1]); w1[2]=f2bf(v2[2]); w1[3]=f2bf(v2[3]);
            w1[4]=f2bf(v3[0]); w1[5]=f2bf(v3[1]); w1[6]=f2bf(v3[2]); w1[7]=f2bf(v3[3]);
            const int c0 = ((ak >> 3) + 0) ^ (ar & 7);
            const int c1 = ((ak >> 3) + 1) ^ (ar & 7);
            *(u16x8*)(&As[ar * BK + (c0 << 3)]) = w0;
            *(u16x8*)(&As[ar * BK + (c1 << 3)]) = w1;
        }
        {
            const ushort* bp = BT + (size_t)bcol * FIN + k0;
#pragma unroll
            for (int j = 0; j < 4; ++j) {
                const int c = bkc + j;
                u16x8 bv = *(const u16x8*)(bp + (c << 3));
                *(u16x8*)(&Bs[bcol * BK + ((c ^ (bcol & 7)) << 3)]) = bv;
            }
        }
        __syncthreads();

#pragma unroll
        for (int kk = 0; kk < 2; ++kk) {
            const int kc = kk * 4 + (lane >> 4);
            bf16x8 af[2], bfr[8];
#pragma unroll
            for (int m = 0; m < 2; ++m) {
                const int row = wm * 32 + m * 16 + (lane & 15);
                af[m] = *(const bf16x8*)(&As[row * BK + ((kc ^ (row & 7)) << 3)]);
            }
#pragma unroll
            for (int n = 0; n < 8; ++n) {
                const int col = wn * 128 + n * 16 + (lane & 15);
                bfr[n] = *(const bf16x8*)(&Bs[col * BK + ((kc ^ (col & 7)) << 3)]);
            }
#pragma unroll
            for (int m = 0; m < 2; ++m)
#pragma unroll
                for (int n = 0; n < 8; ++n)
                    acc[m][n] = __builtin_amdgcn_mfma_f32_16x16x32_bf16(
                        af[m], bfr[n], acc[m][n], 0, 0, 0);
        }
        __syncthreads();
    }

    const int cbase = wn * 128 + (lane & 15);
#pragma unroll
    for (int m = 0; m < 2; ++m) {
#pragma unroll
        for (int reg = 0; reg < 4; ++reg) {
            const int r = brow + wm * 32 + m * 16 + (lane >> 4) * 4 + reg;
            if (r < M) {
#pragma unroll
                for (int n = 0; n < 8; ++n) {
                    Cbf[(size_t)r * FOUT + cbase + n * 16] = f2bf(acc[m][n][reg]);
                }
            }
        }
    }
}

// ---------------- f1,f2 from bf16 seq (wave per row) ----------------
__global__ __launch_bounds__(256) void f1f2_kernel(
    const ushort* __restrict__ seq, const float* __restrict__ a1,
    const float* __restrict__ a2, const float* __restrict__ b1,
    const float* __restrict__ b2, float* __restrict__ f1,
    float* __restrict__ f2, int N)
{
    const int w = threadIdx.x >> 6, lane = threadIdx.x & 63;
    const int row = blockIdx.x * 4 + w;
    if (row >= N) return;
    const ushort4 sv = ((const ushort4*)(seq + (size_t)row * FOUT))[lane];
    const float4 a1v = *(const float4*)(a1 + lane * 4);
    const float4 a2v = *(const float4*)(a2 + lane * 4);
    const float s0 = bf2f(sv.x), s1v = bf2f(sv.y), s2v = bf2f(sv.z), s3 = bf2f(sv.w);
    float s1 = s0 * a1v.x + s1v * a1v.y + s2v * a1v.z + s3 * a1v.w;
    float s2 = s0 * a2v.x + s1v * a2v.y + s2v * a2v.z + s3 * a2v.w;
#pragma unroll
    for (int off = 32; off; off >>= 1) {
        s1 += __shfl_xor(s1, off);
        s2 += __shfl_xor(s2, off);
    }
    if (lane == 0) {
        f1[row] = s1 + b1[0];
        f2[row] = s2 + b2[0];
    }
}

// ---------------- pos: per-edge slot within its src row (fused histogram) ----------------
__global__ void pos_kernel(const int* __restrict__ src, int* __restrict__ cnt,
                           int* __restrict__ pos, int E)
{
    int i = (blockIdx.x * blockDim.x + threadIdx.x) * 4;
    if (i + 4 <= E) {
        const int4 s = *(const int4*)(src + i);
        int4 p;
        p.x = atomicAdd(&cnt[s.x], 1);
        p.y = atomicAdd(&cnt[s.y], 1);
        p.z = atomicAdd(&cnt[s.z], 1);
        p.w = atomicAdd(&cnt[s.w], 1);
        *(int4*)(pos + i) = p;
    } else {
        for (; i < E; ++i) pos[i] = atomicAdd(&cnt[src[i]], 1);
    }
}

// ---------------- 3-stage scan: cnt -> rowoff ----------------
__global__ __launch_bounds__(1024) void scan_blk(const int* __restrict__ cnt,
                                                 int* __restrict__ btot, int N)
{
    __shared__ int s[1024];
    const int t = threadIdx.x;
    const int idx = blockIdx.x * 1024 + t;
    s[t] = (idx < N) ? cnt[idx] : 0;
    __syncthreads();
    for (int off = 512; off; off >>= 1) {
        if (t < off) s[t] += s[t + off];
        __syncthreads();
    }
    if (t == 0) btot[blockIdx.x] = s[0];
}

__global__ __launch_bounds__(64) void scan_top(const int* __restrict__ btot,
                                               int* __restrict__ boff, int nb)
{
    const int t = threadIdx.x;
    const int mine = (t < nb) ? btot[t] : 0;
    int v = mine;
#pragma unroll
    for (int off = 1; off < 64; off <<= 1) {
        const int u = __shfl_up(v, off);
        if (t >= off) v += u;
    }
    if (t < nb) boff[t] = v - mine;   // exclusive prefix
}

__global__ __launch_bounds__(1024) void scan_out(const int* __restrict__ cnt,
                                                 const int* __restrict__ boff,
                                                 int* __restrict__ rowoff, int N)
{
    __shared__ int s[1024];
    const int t = threadIdx.x;
    const int b = blockIdx.x;
    const int idx = b * 1024 + t;
    const int v = (idx < N) ? cnt[idx] : 0;
    s[t] = v;
    __syncthreads();
    for (int off = 1; off < 1024; off <<= 1) {
        const int u = (t >= off) ? s[t - off] : 0;
        __syncthreads();
        s[t] += u;
        __syncthreads();
    }
    if (idx < N)     rowoff[idx] = boff[b] + s[t] - v;
    if (idx == N - 1) rowoff[N]  = boff[b] + s[t];
}

// ---------------- scatter: pd[csr_pos] = {p, dst}, atomic-free ----------------
// No max-subtraction needed: values in [0,1), f1,f2 ~ N(0,1) -> exp(logit) far from
// f32 overflow; coefs identical in exact math.
__global__ void scatter_p(const int* __restrict__ src, const int* __restrict__ dst,
                          const float* __restrict__ values, const int* __restrict__ pos,
                          const float* __restrict__ f1, const float* __restrict__ f2,
                          const int* __restrict__ row_off,
                          unsigned long long* __restrict__ pd, int E)
{
    const int i = blockIdx.x * blockDim.x + threadIdx.x;
    if (i < E) {
        const int s = src[i];
        const int d = dst[i];
        float lg = values[i] * (f1[s] + f2[d]);
        lg = (lg > 0.f) ? lg : LRELU * lg;
        const float p = __expf(lg);
        union { float f; uint32_t u; } pu; pu.f = p;
        const unsigned long long rec = (unsigned long long)pu.u |
                                       ((unsigned long long)(uint32_t)d << 32);
        __builtin_nontemporal_store(rec, &pd[row_off[s] + pos[i]]);
    }
}

// ---------------- spmm: single-pass SPMM + normalize + bias + ELU ----------------
__global__ __launch_bounds__(256) void spmm_kernel(
    const ushort* __restrict__ seq, const unsigned long long* __restrict__ pd,
    const int* __restrict__ row_off, const float* __restrict__ b_out,
    float* __restrict__ out, int N)
{
    const int w = threadIdx.x >> 6, lane = threadIdx.x & 63;
    const int row = blockIdx.x * 4 + w;
    if (row >= N) return;
    const int start = row_off[row], end = row_off[row + 1];

    float4 a0 = make_float4(0.f,0.f,0.f,0.f), a1 = a0, a2 = a0, a3 = a0;
    float den0 = 0.f, den1 = 0.f, den2 = 0.f, den3 = 0.f;
    int t = start;
    for (; t + 4 <= end; t += 4) {
        const unsigned long long q0 = __builtin_nontemporal_load(&pd[t]);
        const unsigned long long q1 = __builtin_nontemporal_load(&pd[t + 1]);
        const unsigned long long q2 = __builtin_nontemporal_load(&pd[t + 2]);
        const unsigned long long q3 = __builtin_nontemporal_load(&pd[t + 3]);
        const float p0 = __uint_as_float((uint32_t)q0), p1 = __uint_as_float((uint32_t)q1);
        const float p2 = __uint_as_float((uint32_t)q2), p3 = __uint_as_float((uint32_t)q3);
        const int d0 = (int)(q0 >> 32), d1 = (int)(q1 >> 32);
        const int d2 = (int)(q2 >> 32), d3 = (int)(q3 >> 32);
        const ushort4 s0 = ((const ushort4*)(seq + (size_t)d0 * FOUT))[lane];
        const ushort4 s1 = ((const ushort4*)(seq + (size_t)d1 * FOUT))[lane];
        const ushort4 s2 = ((const ushort4*)(seq + (size_t)d2 * FOUT))[lane];
        const ushort4 s3 = ((const ushort4*)(seq + (size_t)d3 * FOUT))[lane];
        den0 += p0; den1 += p1; den2 += p2; den3 += p3;
        a0.x += p0 * bf2f(s0.x); a0.y += p0 * bf2f(s0.y);
        a0.z += p0 * bf2f(s0.z); a0.w += p0 * bf2f(s0.w);
        a1.x += p1 * bf2f(s1.x); a1.y += p1 * bf2f(s1.y);
        a1.z += p1 * bf2f(s1.z); a1.w += p1 * bf2f(s1.w);
        a2.x += p2 * bf2f(s2.x); a2.y += p2 * bf2f(s2.y);
        a2.z += p2 * bf2f(s2.z); a2.w += p2 * bf2f(s2.w);
        a3.x += p3 * bf2f(s3.x); a3.y += p3 * bf2f(s3.y);
        a3.z += p3 * bf2f(s3.z); a3.w += p3 * bf2f(s3.w);
    }
    for (; t < end; ++t) {
        const unsigned long long q0 = __builtin_nontemporal_load(&pd[t]);
        const float p0 = __uint_as_float((uint32_t)q0);
        const int d0 = (int)(q0 >> 32);
        const ushort4 s0 = ((const ushort4*)(seq + (size_t)d0 * FOUT))[lane];
        den0 += p0;
        a0.x += p0 * bf2f(s0.x); a0.y += p0 * bf2f(s0.y);
        a0.z += p0 * bf2f(s0.z); a0.w += p0 * bf2f(s0.w);
    }
    const float denom = (den0 + den1) + (den2 + den3);
    const float inv = (end > start) ? 1.f / denom : 0.f;
    const float4 bo = *(const float4*)(b_out + lane * 4);
    f32x4 o;
    o[0] = ((a0.x + a1.x) + (a2.x + a3.x)) * inv + bo.x;
    o[1] = ((a0.y + a1.y) + (a2.y + a3.y)) * inv + bo.y;
    o[2] = ((a0.z + a1.z) + (a2.z + a3.z)) * inv + bo.z;
    o[3] = ((a0.w + a1.w) + (a2.w + a3.w)) * inv + bo.w;
    o[0] = (o[0] > 0.f) ? o[0] : expm1f(o[0]);
    o[1] = (o[1] > 0.f) ? o[1] : expm1f(o[1]);
    o[2] = (o[2] > 0.f) ? o[2] : expm1f(o[2]);
    o[3] = (o[3] > 0.f) ? o[3] : expm1f(o[3]);
    __builtin_nontemporal_store(o, (f32x4*)(out + (size_t)row * FOUT + lane * 4));
}

extern "C" void kernel_launch(void* const* d_in, const int* in_sizes, int n_in,
                              void* d_out, int out_size, void* d_ws, size_t ws_size,
                              hipStream_t stream)
{
    const float* x      = (const float*)d_in[0];
    const float* values = (const float*)d_in[1];
    const int*   ei     = (const int*)d_in[2];
    const float* W      = (const float*)d_in[3];
    const float* a1     = (const float*)d_in[4];
    const float* b1     = (const float*)d_in[5];
    const float* a2     = (const float*)d_in[6];
    const float* b2     = (const float*)d_in[7];
    const float* b_out  = (const float*)d_in[8];
    float* out = (float*)d_out;

    const int N = in_sizes[0] / FIN;   // 63001
    const int E = in_sizes[1];         // 2,000,000
    const int* src = ei;
    const int* dst = ei + E;

    auto alignup = [](size_t v) { return (v + 255) & ~(size_t)255; };
    char* ws = (char*)d_ws;
    size_t off = 0;
    ushort* seqbf = (ushort*)(ws + off); off = alignup(off + (size_t)N * FOUT * 2);
    ushort* WT    = (ushort*)(ws + off); off = alignup(off + (size_t)FIN * FOUT * 2);
    float*  f1    = (float*)(ws + off);  off = alignup(off + (size_t)N * 4);
    float*  f2    = (float*)(ws + off);  off = alignup(off + (size_t)N * 4);
    int*    cnt   = (int*)(ws + off);    off = alignup(off + (size_t)N * 4);
    int*    rowoff= (int*)(ws + off);    off = alignup(off + (size_t)(N + 1) * 4);
    int*    btot  = (int*)(ws + off);    off = alignup(off + (size_t)64 * 4);
    int*    boff  = (int*)(ws + off);    off = alignup(off + (size_t)64 * 4);
    int*    pos   = (int*)(ws + off);    off = alignup(off + (size_t)E * 4);
    unsigned long long* pd = (unsigned long long*)(ws + off); off = alignup(off + (size_t)E * 8);
    (void)ws_size;

    const int nb = (N + 1023) / 1024;  // 62

    hipMemsetAsync(cnt, 0, (size_t)N * 4, stream);

    pos_kernel<<<(E / 4 + 255) / 256, 256, 0, stream>>>(src, cnt, pos, E);
    scan_blk<<<nb, 1024, 0, stream>>>(cnt, btot, N);
    scan_top<<<1, 64, 0, stream>>>(btot, boff, nb);
    scan_out<<<nb, 1024, 0, stream>>>(cnt, boff, rowoff, N);

    prep_wt<<<(FIN * FOUT + 255) / 256, 256, 0, stream>>>(W, WT);
    gemm_bf16<<<(N + BM - 1) / BM, 512, 0, stream>>>(x, WT, seqbf, N);
    f1f2_kernel<<<(N + 3) / 4, 256, 0, stream>>>(seqbf, a1, a2, b1, b2, f1, f2, N);

    scatter_p<<<(E + 255) / 256, 256, 0, stream>>>(src, dst, values, pos, f1, f2,
                                                   rowoff, pd, E);

    spmm_kernel<<<(N + 3) / 4, 256, 0, stream>>>(seqbf, pd, rowoff, b_out, out, N);
}

// Round 5
// 357.506 us; speedup vs baseline: 2.8100x; 1.0964x over previous
//
#include <hip/hip_runtime.h>
#include <cstdint>
#include <cstddef>

#define FIN 512
#define FOUT 256
#define LRELU 0.2f
#define NBKT 8           // dst buckets (8192 rows x 512B = 4MB = one XCD L2)
#define BSH 13           // dst >> 13

typedef __attribute__((ext_vector_type(8))) short bf16x8;
typedef __attribute__((ext_vector_type(8))) unsigned short u16x8;
typedef __attribute__((ext_vector_type(4))) float f32x4;

__device__ inline ushort f2bf(float f) {
    union { float f; uint32_t u; } c; c.f = f;
    uint32_t u = c.u;
    return (ushort)((u + 0x7FFF + ((u >> 16) & 1)) >> 16);   // RNE
}
__device__ inline float bf2f(ushort h) {
    union { uint32_t u; float f; } c; c.u = ((uint32_t)h) << 16;
    return c.f;
}

// ---------------- prep: WT_bf[n][k] = bf16(W[k][n]) ----------------
__global__ void prep_wt(const float* __restrict__ W, ushort* __restrict__ WT)
{
    const int idx = blockIdx.x * blockDim.x + threadIdx.x;
    if (idx < FIN * FOUT) {
        const int k = idx >> 8, n = idx & 255;
        WT[(size_t)n * FIN + k] = f2bf(W[(size_t)k * FOUT + n]);
    }
}

// ---------------- gemm + fused f1/f2: seq_bf = bf16(x@W), f1=seq@a1+b1, f2=seq@a2+b2 ----------------
#define BM 128
#define BK 64
__global__ __launch_bounds__(512) void gemm_bf16(
    const float* __restrict__ A,      // [M,512] f32
    const ushort* __restrict__ BT,    // [256,512] bf16, n-major
    ushort* __restrict__ Cbf,         // [M,256] bf16
    const float* __restrict__ a1, const float* __restrict__ a2,
    const float* __restrict__ b1, const float* __restrict__ b2,
    float* __restrict__ f1, float* __restrict__ f2,
    int M)
{
    __shared__ ushort As[BM * BK];    // 16 KB, 16B-chunk XOR swizzle
    __shared__ ushort Bs[FOUT * BK];  // 32 KB
    __shared__ float f1s[BM][2];
    __shared__ float f2s[BM][2];
    const int t = threadIdx.x;
    const int lane = t & 63, w = t >> 6;
    const int wm = w & 3, wn = w >> 2;
    const int brow = blockIdx.x * BM;

    f32x4 acc[2][8] = {};

    const int ar = t >> 2;
    const int ak = (t & 3) << 4;
    const int bcol = t >> 1;
    const int bkc = (t & 1) * 4;

    for (int k0 = 0; k0 < FIN; k0 += BK) {
        {
            f32x4 v0, v1, v2, v3;
            const int grow = brow + ar;
            if (grow < M) {
                const f32x4* p = (const f32x4*)(A + (size_t)grow * FIN + k0 + ak);
                v0 = __builtin_nontemporal_load(p + 0);
                v1 = __builtin_nontemporal_load(p + 1);
                v2 = __builtin_nontemporal_load(p + 2);
                v3 = __builtin_nontemporal_load(p + 3);
            } else {
                v0 = v1 = v2 = v3 = (f32x4)0.f;
            }
            u16x8 w0, w1;
            w0[0]=f2bf(v0[0]); w0[1]=f2bf(v0[1]); w0[2]=f2bf(v0[2]); w0[3]=f2bf(v0[3]);
            w0[4]=f2bf(v1[0]); w0[5]=f2bf(v1[1]); w0[6]=f2bf(v1[2]); w0[7]=f2bf(v1[3]);
            w1[0]=f2bf(v2[0]); w1[1]=f2bf(v2[1]); w1[2]=f2bf(v2[2]); w1[3]=f2bf(v2[3]);
            w1[4]=f2bf(v3[0]); w1[5]=f2bf(v3[1]); w1[6]=f2bf(v3[2]); w1[7]=f2bf(v3[3]);
            const int c0 = ((ak >> 3) + 0) ^ (ar & 7);
            const int c1 = ((ak >> 3) + 1) ^ (ar & 7);
            *(u16x8*)(&As[ar * BK + (c0 << 3)]) = w0;
            *(u16x8*)(&As[ar * BK + (c1 << 3)]) = w1;
        }
        {
            const ushort* bp = BT + (size_t)bcol * FIN + k0;
#pragma unroll
            for (int j = 0; j < 4; ++j) {
                const int c = bkc + j;
                u16x8 bv = *(const u16x8*)(bp + (c << 3));
                *(u16x8*)(&Bs[bcol * BK + ((c ^ (bcol & 7)) << 3)]) = bv;
            }
        }
        __syncthreads();

#pragma unroll
        for (int kk = 0; kk < 2; ++kk) {
            const int kc = kk * 4 + (lane >> 4);
            bf16x8 af[2], bfr[8];
#pragma unroll
            for (int m = 0; m < 2; ++m) {
                const int row = wm * 32 + m * 16 + (lane & 15);
                af[m] = *(const bf16x8*)(&As[row * BK + ((kc ^ (row & 7)) << 3)]);
            }
#pragma unroll
            for (int n = 0; n < 8; ++n) {
                const int col = wn * 128 + n * 16 + (lane & 15);
                bfr[n] = *(const bf16x8*)(&Bs[col * BK + ((kc ^ (col & 7)) << 3)]);
            }
#pragma unroll
            for (int m = 0; m < 2; ++m)
#pragma unroll
                for (int n = 0; n < 8; ++n)
                    acc[m][n] = __builtin_amdgcn_mfma_f32_16x16x32_bf16(
                        af[m], bfr[n], acc[m][n], 0, 0, 0);
        }
        __syncthreads();
    }

    // ---- C write + fused f1/f2 partials ----
    // C/D layout: col = wn*128 + n*16 + (lane&15), row = wm*32 + m*16 + (lane>>4)*4 + reg
    float a1c[8], a2c[8];
#pragma unroll
    for (int n = 0; n < 8; ++n) {
        const int col = wn * 128 + n * 16 + (lane & 15);
        a1c[n] = a1[col];
        a2c[n] = a2[col];
    }
    const int cbase = wn * 128 + (lane & 15);
#pragma unroll
    for (int m = 0; m < 2; ++m) {
#pragma unroll
        for (int reg = 0; reg < 4; ++reg) {
            const int rloc = wm * 32 + m * 16 + (lane >> 4) * 4 + reg;
            const int r = brow + rloc;
            float p1 = 0.f, p2 = 0.f;
#pragma unroll
            for (int n = 0; n < 8; ++n) {
                p1 += acc[m][n][reg] * a1c[n];
                p2 += acc[m][n][reg] * a2c[n];
            }
#pragma unroll
            for (int off = 1; off < 16; off <<= 1) {   // reduce over lane&15
                p1 += __shfl_xor(p1, off);
                p2 += __shfl_xor(p2, off);
            }
            if ((lane & 15) == 0) {
                f1s[rloc][wn] = p1;
                f2s[rloc][wn] = p2;
            }
            if (r < M) {
#pragma unroll
                for (int n = 0; n < 8; ++n)
                    Cbf[(size_t)r * FOUT + cbase + n * 16] = f2bf(acc[m][n][reg]);
            }
        }
    }
    __syncthreads();
    if (t < BM) {
        const int r = brow + t;
        if (r < M) {
            f1[r] = f1s[t][0] + f1s[t][1] + b1[0];
            f2[r] = f2s[t][0] + f2s[t][1] + b2[0];
        }
    }
}

// ---------------- pos: per-edge slot within (src,bucket) key ----------------
__global__ void pos_kernel(const int* __restrict__ src, const int* __restrict__ dst,
                           int* __restrict__ cnt, int* __restrict__ pos, int E)
{
    int i = (blockIdx.x * blockDim.x + threadIdx.x) * 4;
    if (i + 4 <= E) {
        const int4 s = *(const int4*)(src + i);
        const int4 d = *(const int4*)(dst + i);
        int4 p;
        p.x = atomicAdd(&cnt[s.x * NBKT + (d.x >> BSH)], 1);
        p.y = atomicAdd(&cnt[s.y * NBKT + (d.y >> BSH)], 1);
        p.z = atomicAdd(&cnt[s.z * NBKT + (d.z >> BSH)], 1);
        p.w = atomicAdd(&cnt[s.w * NBKT + (d.w >> BSH)], 1);
        *(int4*)(pos + i) = p;
    } else {
        for (; i < E; ++i) pos[i] = atomicAdd(&cnt[src[i] * NBKT + (dst[i] >> BSH)], 1);
    }
}

// ---------------- 3-stage scan over K = N*NBKT keys ----------------
__global__ __launch_bounds__(1024) void scan_blk(const int* __restrict__ cnt,
                                                 int* __restrict__ btot, int K)
{
    __shared__ int s[1024];
    const int t = threadIdx.x;
    const int idx = blockIdx.x * 1024 + t;
    s[t] = (idx < K) ? cnt[idx] : 0;
    __syncthreads();
    for (int off = 512; off; off >>= 1) {
        if (t < off) s[t] += s[t + off];
        __syncthreads();
    }
    if (t == 0) btot[blockIdx.x] = s[0];
}

__global__ __launch_bounds__(1024) void scan_top(const int* __restrict__ btot,
                                                 int* __restrict__ boff, int nb)
{
    __shared__ int s[1024];
    const int t = threadIdx.x;
    const int mine = (t < nb) ? btot[t] : 0;
    s[t] = mine;
    __syncthreads();
    for (int off = 1; off < 1024; off <<= 1) {
        const int u = (t >= off) ? s[t - off] : 0;
        __syncthreads();
        s[t] += u;
        __syncthreads();
    }
    if (t < nb) boff[t] = s[t] - mine;   // exclusive
}

__global__ __launch_bounds__(1024) void scan_out(const int* __restrict__ cnt,
                                                 const int* __restrict__ boff,
                                                 int* __restrict__ koff, int K)
{
    __shared__ int s[1024];
    const int t = threadIdx.x;
    const int b = blockIdx.x;
    const int idx = b * 1024 + t;
    const int v = (idx < K) ? cnt[idx] : 0;
    s[t] = v;
    __syncthreads();
    for (int off = 1; off < 1024; off <<= 1) {
        const int u = (t >= off) ? s[t - off] : 0;
        __syncthreads();
        s[t] += u;
        __syncthreads();
    }
    if (idx < K)      koff[idx] = boff[b] + s[t] - v;
    if (idx == K - 1) koff[K]   = boff[b] + s[t];
}

// ---------------- scatter: pd[csr_pos] = {p, dst}, atomic-free, bucket-ordered ----------------
// No max-subtraction: values in [0,1), f1,f2 ~ N(0,1) -> exp(logit) far from f32 overflow.
__global__ void scatter_p(const int* __restrict__ src, const int* __restrict__ dst,
                          const float* __restrict__ values, const int* __restrict__ pos,
                          const float* __restrict__ f1, const float* __restrict__ f2,
                          const int* __restrict__ koff,
                          unsigned long long* __restrict__ pd, int E)
{
    const int i = blockIdx.x * blockDim.x + threadIdx.x;
    if (i < E) {
        const int s = src[i];
        const int d = dst[i];
        float lg = values[i] * (f1[s] + f2[d]);
        lg = (lg > 0.f) ? lg : LRELU * lg;
        const float p = __expf(lg);
        union { float f; uint32_t u; } pu; pu.f = p;
        const unsigned long long rec = (unsigned long long)pu.u |
                                       ((unsigned long long)(uint32_t)d << 32);
        __builtin_nontemporal_store(rec, &pd[koff[s * NBKT + (d >> BSH)] + pos[i]]);
    }
}

// ---------------- spmm: single-pass SPMM + normalize + bias + ELU ----------------
__global__ __launch_bounds__(256) void spmm_kernel(
    const ushort* __restrict__ seq, const unsigned long long* __restrict__ pd,
    const int* __restrict__ koff, const float* __restrict__ b_out,
    float* __restrict__ out, int N)
{
    const int w = threadIdx.x >> 6, lane = threadIdx.x & 63;
    const int row = blockIdx.x * 4 + w;
    if (row >= N) return;
    const int start = koff[row * NBKT], end = koff[(row + 1) * NBKT];

    float4 a0 = make_float4(0.f,0.f,0.f,0.f), a1 = a0, a2 = a0, a3 = a0;
    float den0 = 0.f, den1 = 0.f, den2 = 0.f, den3 = 0.f;
    int t = start;
    for (; t + 4 <= end; t += 4) {
        const unsigned long long q0 = pd[t];
        const unsigned long long q1 = pd[t + 1];
        const unsigned long long q2 = pd[t + 2];
        const unsigned long long q3 = pd[t + 3];
        const float p0 = __uint_as_float((uint32_t)q0), p1 = __uint_as_float((uint32_t)q1);
        const float p2 = __uint_as_float((uint32_t)q2), p3 = __uint_as_float((uint32_t)q3);
        const int d0 = (int)(q0 >> 32), d1 = (int)(q1 >> 32);
        const int d2 = (int)(q2 >> 32), d3 = (int)(q3 >> 32);
        const ushort4 s0 = ((const ushort4*)(seq + (size_t)d0 * FOUT))[lane];
        const ushort4 s1 = ((const ushort4*)(seq + (size_t)d1 * FOUT))[lane];
        const ushort4 s2 = ((const ushort4*)(seq + (size_t)d2 * FOUT))[lane];
        const ushort4 s3 = ((const ushort4*)(seq + (size_t)d3 * FOUT))[lane];
        den0 += p0; den1 += p1; den2 += p2; den3 += p3;
        a0.x += p0 * bf2f(s0.x); a0.y += p0 * bf2f(s0.y);
        a0.z += p0 * bf2f(s0.z); a0.w += p0 * bf2f(s0.w);
        a1.x += p1 * bf2f(s1.x); a1.y += p1 * bf2f(s1.y);
        a1.z += p1 * bf2f(s1.z); a1.w += p1 * bf2f(s1.w);
        a2.x += p2 * bf2f(s2.x); a2.y += p2 * bf2f(s2.y);
        a2.z += p2 * bf2f(s2.z); a2.w += p2 * bf2f(s2.w);
        a3.x += p3 * bf2f(s3.x); a3.y += p3 * bf2f(s3.y);
        a3.z += p3 * bf2f(s3.z); a3.w += p3 * bf2f(s3.w);
    }
    for (; t < end; ++t) {
        const unsigned long long q0 = pd[t];
        const float p0 = __uint_as_float((uint32_t)q0);
        const int d0 = (int)(q0 >> 32);
        const ushort4 s0 = ((const ushort4*)(seq + (size_t)d0 * FOUT))[lane];
        den0 += p0;
        a0.x += p0 * bf2f(s0.x); a0.y += p0 * bf2f(s0.y);
        a0.z += p0 * bf2f(s0.z); a0.w += p0 * bf2f(s0.w);
    }
    const float denom = (den0 + den1) + (den2 + den3);
    const float inv = (end > start) ? 1.f / denom : 0.f;
    const float4 bo = *(const float4*)(b_out + lane * 4);
    f32x4 o;
    o[0] = ((a0.x + a1.x) + (a2.x + a3.x)) * inv + bo.x;
    o[1] = ((a0.y + a1.y) + (a2.y + a3.y)) * inv + bo.y;
    o[2] = ((a0.z + a1.z) + (a2.z + a3.z)) * inv + bo.z;
    o[3] = ((a0.w + a1.w) + (a2.w + a3.w)) * inv + bo.w;
    o[0] = (o[0] > 0.f) ? o[0] : expm1f(o[0]);
    o[1] = (o[1] > 0.f) ? o[1] : expm1f(o[1]);
    o[2] = (o[2] > 0.f) ? o[2] : expm1f(o[2]);
    o[3] = (o[3] > 0.f) ? o[3] : expm1f(o[3]);
    __builtin_nontemporal_store(o, (f32x4*)(out + (size_t)row * FOUT + lane * 4));
}

extern "C" void kernel_launch(void* const* d_in, const int* in_sizes, int n_in,
                              void* d_out, int out_size, void* d_ws, size_t ws_size,
                              hipStream_t stream)
{
    const float* x      = (const float*)d_in[0];
    const float* values = (const float*)d_in[1];
    const int*   ei     = (const int*)d_in[2];
    const float* W      = (const float*)d_in[3];
    const float* a1     = (const float*)d_in[4];
    const float* b1     = (const float*)d_in[5];
    const float* a2     = (const float*)d_in[6];
    const float* b2     = (const float*)d_in[7];
    const float* b_out  = (const float*)d_in[8];
    float* out = (float*)d_out;

    const int N = in_sizes[0] / FIN;   // 63001
    const int E = in_sizes[1];         // 2,000,000
    const int* src = ei;
    const int* dst = ei + E;
    const int K = N * NBKT;

    auto alignup = [](size_t v) { return (v + 255) & ~(size_t)255; };
    char* ws = (char*)d_ws;
    size_t off = 0;
    ushort* seqbf = (ushort*)(ws + off); off = alignup(off + (size_t)N * FOUT * 2);
    ushort* WT    = (ushort*)(ws + off); off = alignup(off + (size_t)FIN * FOUT * 2);
    float*  f1    = (float*)(ws + off);  off = alignup(off + (size_t)N * 4);
    float*  f2    = (float*)(ws + off);  off = alignup(off + (size_t)N * 4);
    int*    cnt   = (int*)(ws + off);    off = alignup(off + (size_t)K * 4);
    int*    koff  = (int*)(ws + off);    off = alignup(off + (size_t)(K + 1) * 4);
    int*    btot  = (int*)(ws + off);    off = alignup(off + (size_t)1024 * 4);
    int*    boff  = (int*)(ws + off);    off = alignup(off + (size_t)1024 * 4);
    int*    pos   = (int*)(ws + off);    off = alignup(off + (size_t)E * 4);
    unsigned long long* pd = (unsigned long long*)(ws + off); off = alignup(off + (size_t)E * 8);
    (void)ws_size;

    const int nbk = (K + 1023) / 1024;   // 493

    hipMemsetAsync(cnt, 0, (size_t)K * 4, stream);

    pos_kernel<<<(E / 4 + 255) / 256, 256, 0, stream>>>(src, dst, cnt, pos, E);
    scan_blk<<<nbk, 1024, 0, stream>>>(cnt, btot, K);
    scan_top<<<1, 1024, 0, stream>>>(btot, boff, nbk);
    scan_out<<<nbk, 1024, 0, stream>>>(cnt, boff, koff, K);

    prep_wt<<<(FIN * FOUT + 255) / 256, 256, 0, stream>>>(W, WT);
    gemm_bf16<<<(N + BM - 1) / BM, 512, 0, stream>>>(x, WT, seqbf, a1, a2, b1, b2,
                                                     f1, f2, N);

    scatter_p<<<(E + 255) / 256, 256, 0, stream>>>(src, dst, values, pos, f1, f2,
                                                   koff, pd, E);

    spmm_kernel<<<(N + 3) / 4, 256, 0, stream>>>(seqbf, pd, koff, b_out, out, N);
}

// Round 6
// 357.480 us; speedup vs baseline: 2.8102x; 1.0001x over previous
//
#include <hip/hip_runtime.h>
#include <cstdint>
#include <cstddef>

#define FIN 512
#define FOUT 256
#define LRELU 0.2f
#define NBKT 8           // dst buckets (8192 rows x 512B = 4MB = one XCD L2)
#define BSH 13           // dst >> 13

typedef __attribute__((ext_vector_type(8))) short bf16x8;
typedef __attribute__((ext_vector_type(8))) unsigned short u16x8;
typedef __attribute__((ext_vector_type(4))) float f32x4;
typedef _Float16 h16x2 __attribute__((ext_vector_type(2)));

#define PERM_LO 0x05040100u   // {src1.lo16, src0.lo16}  (arg0 = high source)
#define PERM_HI 0x07060302u   // {src1.hi16, src0.hi16}
#define ONE2H   0x3C003C00u   // {1.0h, 1.0h}

__device__ inline ushort f2bf(float f) {
    union { float f; uint32_t u; } c; c.f = f;
    uint32_t u = c.u;
    return (ushort)((u + 0x7FFF + ((u >> 16) & 1)) >> 16);   // RNE
}
__device__ inline ushort f2h(float f) {
    union { _Float16 h; ushort u; } c; c.h = (_Float16)f;    // v_cvt_f16_f32 RNE
    return c.u;
}
__device__ inline h16x2 u2h2(uint32_t u) {
    union { uint32_t u; h16x2 h; } c; c.u = u;
    return c.h;
}

// ---------------- prep: WT_bf[n][k] = bf16(W[k][n])  (bf16 for MFMA B) ----------------
__global__ void prep_wt(const float* __restrict__ W, ushort* __restrict__ WT)
{
    const int idx = blockIdx.x * blockDim.x + threadIdx.x;
    if (idx < FIN * FOUT) {
        const int k = idx >> 8, n = idx & 255;
        WT[(size_t)n * FIN + k] = f2bf(W[(size_t)k * FOUT + n]);
    }
}

// ---------------- gemm + fused f1/f2: seq_h = f16(x@W), f1=seq@a1+b1, f2=seq@a2+b2 ----------------
#define BM 128
#define BK 64
__global__ __launch_bounds__(512) void gemm_bf16(
    const float* __restrict__ A,      // [M,512] f32
    const ushort* __restrict__ BT,    // [256,512] bf16, n-major
    ushort* __restrict__ Ch,          // [M,256] f16
    const float* __restrict__ a1, const float* __restrict__ a2,
    const float* __restrict__ b1, const float* __restrict__ b2,
    float* __restrict__ f1, float* __restrict__ f2,
    int M)
{
    __shared__ ushort As[BM * BK];    // 16 KB, 16B-chunk XOR swizzle
    __shared__ ushort Bs[FOUT * BK];  // 32 KB
    __shared__ float f1s[BM][2];
    __shared__ float f2s[BM][2];
    const int t = threadIdx.x;
    const int lane = t & 63, w = t >> 6;
    const int wm = w & 3, wn = w >> 2;
    const int brow = blockIdx.x * BM;

    f32x4 acc[2][8] = {};

    const int ar = t >> 2;
    const int ak = (t & 3) << 4;
    const int bcol = t >> 1;
    const int bkc = (t & 1) * 4;

    for (int k0 = 0; k0 < FIN; k0 += BK) {
        {
            f32x4 v0, v1, v2, v3;
            const int grow = brow + ar;
            if (grow < M) {
                const f32x4* p = (const f32x4*)(A + (size_t)grow * FIN + k0 + ak);
                v0 = __builtin_nontemporal_load(p + 0);
                v1 = __builtin_nontemporal_load(p + 1);
                v2 = __builtin_nontemporal_load(p + 2);
                v3 = __builtin_nontemporal_load(p + 3);
            } else {
                v0 = v1 = v2 = v3 = (f32x4)0.f;
            }
            u16x8 w0, w1;
            w0[0]=f2bf(v0[0]); w0[1]=f2bf(v0[1]); w0[2]=f2bf(v0[2]); w0[3]=f2bf(v0[3]);
            w0[4]=f2bf(v1[0]); w0[5]=f2bf(v1[1]); w0[6]=f2bf(v1[2]); w0[7]=f2bf(v1[3]);
            w1[0]=f2bf(v2[0]); w1[1]=f2bf(v2[1]); w1[2]=f2bf(v2[2]); w1[3]=f2bf(v2[3]);
            w1[4]=f2bf(v3[0]); w1[5]=f2bf(v3[1]); w1[6]=f2bf(v3[2]); w1[7]=f2bf(v3[3]);
            const int c0 = ((ak >> 3) + 0) ^ (ar & 7);
            const int c1 = ((ak >> 3) + 1) ^ (ar & 7);
            *(u16x8*)(&As[ar * BK + (c0 << 3)]) = w0;
            *(u16x8*)(&As[ar * BK + (c1 << 3)]) = w1;
        }
        {
            const ushort* bp = BT + (size_t)bcol * FIN + k0;
#pragma unroll
            for (int j = 0; j < 4; ++j) {
                const int c = bkc + j;
                u16x8 bv = *(const u16x8*)(bp + (c << 3));
                *(u16x8*)(&Bs[bcol * BK + ((c ^ (bcol & 7)) << 3)]) = bv;
            }
        }
        __syncthreads();

#pragma unroll
        for (int kk = 0; kk < 2; ++kk) {
            const int kc = kk * 4 + (lane >> 4);
            bf16x8 af[2], bfr[8];
#pragma unroll
            for (int m = 0; m < 2; ++m) {
                const int row = wm * 32 + m * 16 + (lane & 15);
                af[m] = *(const bf16x8*)(&As[row * BK + ((kc ^ (row & 7)) << 3)]);
            }
#pragma unroll
            for (int n = 0; n < 8; ++n) {
                const int col = wn * 128 + n * 16 + (lane & 15);
                bfr[n] = *(const bf16x8*)(&Bs[col * BK + ((kc ^ (col & 7)) << 3)]);
            }
#pragma unroll
            for (int m = 0; m < 2; ++m)
#pragma unroll
                for (int n = 0; n < 8; ++n)
                    acc[m][n] = __builtin_amdgcn_mfma_f32_16x16x32_bf16(
                        af[m], bfr[n], acc[m][n], 0, 0, 0);
        }
        __syncthreads();
    }

    // ---- C write (f16) + fused f1/f2 partials ----
    float a1c[8], a2c[8];
#pragma unroll
    for (int n = 0; n < 8; ++n) {
        const int col = wn * 128 + n * 16 + (lane & 15);
        a1c[n] = a1[col];
        a2c[n] = a2[col];
    }
    const int cbase = wn * 128 + (lane & 15);
#pragma unroll
    for (int m = 0; m < 2; ++m) {
#pragma unroll
        for (int reg = 0; reg < 4; ++reg) {
            const int rloc = wm * 32 + m * 16 + (lane >> 4) * 4 + reg;
            const int r = brow + rloc;
            float p1 = 0.f, p2 = 0.f;
#pragma unroll
            for (int n = 0; n < 8; ++n) {
                p1 += acc[m][n][reg] * a1c[n];
                p2 += acc[m][n][reg] * a2c[n];
            }
#pragma unroll
            for (int off = 1; off < 16; off <<= 1) {
                p1 += __shfl_xor(p1, off);
                p2 += __shfl_xor(p2, off);
            }
            if ((lane & 15) == 0) {
                f1s[rloc][wn] = p1;
                f2s[rloc][wn] = p2;
            }
            if (r < M) {
#pragma unroll
                for (int n = 0; n < 8; ++n)
                    Ch[(size_t)r * FOUT + cbase + n * 16] = f2h(acc[m][n][reg]);
            }
        }
    }
    __syncthreads();
    if (t < BM) {
        const int r = brow + t;
        if (r < M) {
            f1[r] = f1s[t][0] + f1s[t][1] + b1[0];
            f2[r] = f2s[t][0] + f2s[t][1] + b2[0];
        }
    }
}

// ---------------- pos: per-edge slot within (src,bucket) key ----------------
__global__ void pos_kernel(const int* __restrict__ src, const int* __restrict__ dst,
                           int* __restrict__ cnt, int* __restrict__ pos, int E)
{
    int i = (blockIdx.x * blockDim.x + threadIdx.x) * 4;
    if (i + 4 <= E) {
        const int4 s = *(const int4*)(src + i);
        const int4 d = *(const int4*)(dst + i);
        int4 p;
        p.x = atomicAdd(&cnt[s.x * NBKT + (d.x >> BSH)], 1);
        p.y = atomicAdd(&cnt[s.y * NBKT + (d.y >> BSH)], 1);
        p.z = atomicAdd(&cnt[s.z * NBKT + (d.z >> BSH)], 1);
        p.w = atomicAdd(&cnt[s.w * NBKT + (d.w >> BSH)], 1);
        *(int4*)(pos + i) = p;
    } else {
        for (; i < E; ++i) pos[i] = atomicAdd(&cnt[src[i] * NBKT + (dst[i] >> BSH)], 1);
    }
}

// ---------------- 3-stage scan over K = N*NBKT keys ----------------
__global__ __launch_bounds__(1024) void scan_blk(const int* __restrict__ cnt,
                                                 int* __restrict__ btot, int K)
{
    __shared__ int s[1024];
    const int t = threadIdx.x;
    const int idx = blockIdx.x * 1024 + t;
    s[t] = (idx < K) ? cnt[idx] : 0;
    __syncthreads();
    for (int off = 512; off; off >>= 1) {
        if (t < off) s[t] += s[t + off];
        __syncthreads();
    }
    if (t == 0) btot[blockIdx.x] = s[0];
}

__global__ __launch_bounds__(1024) void scan_top(const int* __restrict__ btot,
                                                 int* __restrict__ boff, int nb)
{
    __shared__ int s[1024];
    const int t = threadIdx.x;
    const int mine = (t < nb) ? btot[t] : 0;
    s[t] = mine;
    __syncthreads();
    for (int off = 1; off < 1024; off <<= 1) {
        const int u = (t >= off) ? s[t - off] : 0;
        __syncthreads();
        s[t] += u;
        __syncthreads();
    }
    if (t < nb) boff[t] = s[t] - mine;   // exclusive
}

__global__ __launch_bounds__(1024) void scan_out(const int* __restrict__ cnt,
                                                 const int* __restrict__ boff,
                                                 int* __restrict__ koff, int K)
{
    __shared__ int s[1024];
    const int t = threadIdx.x;
    const int b = blockIdx.x;
    const int idx = b * 1024 + t;
    const int v = (idx < K) ? cnt[idx] : 0;
    s[t] = v;
    __syncthreads();
    for (int off = 1; off < 1024; off <<= 1) {
        const int u = (t >= off) ? s[t - off] : 0;
        __syncthreads();
        s[t] += u;
        __syncthreads();
    }
    if (idx < K)      koff[idx] = boff[b] + s[t] - v;
    if (idx == K - 1) koff[K]   = boff[b] + s[t];
}

// ---------------- scatter: pd[csr_pos] = {f16(p), dst}, atomic-free ----------------
// No max-subtraction: values in [0,1), f1,f2 ~ N(0,1) -> p = exp(lg) in [e^-2, ~e^10],
// comfortably inside f16 range [6e-5, 65504]. Coefs use the same f16(p) in numerator
// and denominator, so they still sum to exactly 1.
__global__ void scatter_p(const int* __restrict__ src, const int* __restrict__ dst,
                          const float* __restrict__ values, const int* __restrict__ pos,
                          const float* __restrict__ f1, const float* __restrict__ f2,
                          const int* __restrict__ koff,
                          unsigned long long* __restrict__ pd, int E)
{
    const int i = blockIdx.x * blockDim.x + threadIdx.x;
    if (i < E) {
        const int s = src[i];
        const int d = dst[i];
        float lg = values[i] * (f1[s] + f2[d]);
        lg = (lg > 0.f) ? lg : LRELU * lg;
        const float p = __expf(lg);
        const unsigned long long rec = (unsigned long long)f2h(p) |
                                       ((unsigned long long)(uint32_t)d << 32);
        __builtin_nontemporal_store(rec, &pd[koff[s * NBKT + (d >> BSH)] + pos[i]]);
    }
}

// ---------------- spmm: dot2-f16 SPMM + normalize + bias + ELU ----------------
__global__ __launch_bounds__(256) void spmm_kernel(
    const ushort* __restrict__ seq,   // f16 [N][256]
    const unsigned long long* __restrict__ pd,
    const int* __restrict__ koff, const float* __restrict__ b_out,
    float* __restrict__ out, int N)
{
    const int w = threadIdx.x >> 6, lane = threadIdx.x & 63;
    const int row = blockIdx.x * 4 + w;
    if (row >= N) return;
    // wave-uniform bounds as scalars -> pd[t] becomes a scalar (s_load) stream
    const int start = __builtin_amdgcn_readfirstlane(koff[row * NBKT]);
    const int end   = __builtin_amdgcn_readfirstlane(koff[(row + 1) * NBKT]);

    const ushort* seql = seq + lane * 4;      // lane covers cols lane*4 .. +3
    float acc0 = 0.f, acc1 = 0.f, acc2 = 0.f, acc3 = 0.f, den = 0.f;
    const h16x2 one2 = u2h2(ONE2H);

    int t = start;
    for (; t + 4 <= end; t += 4) {
        const unsigned long long q0 = pd[t],     q1 = pd[t + 1];
        const unsigned long long q2 = pd[t + 2], q3 = pd[t + 3];
        const int d0 = (int)(q0 >> 32), d1 = (int)(q1 >> 32);
        const int d2 = (int)(q2 >> 32), d3 = (int)(q3 >> 32);
        const uint2 s0 = *(const uint2*)(seql + (size_t)d0 * FOUT);
        const uint2 s1 = *(const uint2*)(seql + (size_t)d1 * FOUT);
        const uint2 s2 = *(const uint2*)(seql + (size_t)d2 * FOUT);
        const uint2 s3 = *(const uint2*)(seql + (size_t)d3 * FOUT);
        const h16x2 ppA = u2h2(((uint32_t)q0 & 0xffffu) | ((uint32_t)q1 << 16));
        const h16x2 ppB = u2h2(((uint32_t)q2 & 0xffffu) | ((uint32_t)q3 << 16));
        acc0 = __builtin_amdgcn_fdot2(ppA, u2h2(__builtin_amdgcn_perm(s1.x, s0.x, PERM_LO)), acc0, false);
        acc1 = __builtin_amdgcn_fdot2(ppA, u2h2(__builtin_amdgcn_perm(s1.x, s0.x, PERM_HI)), acc1, false);
        acc2 = __builtin_amdgcn_fdot2(ppA, u2h2(__builtin_amdgcn_perm(s1.y, s0.y, PERM_LO)), acc2, false);
        acc3 = __builtin_amdgcn_fdot2(ppA, u2h2(__builtin_amdgcn_perm(s1.y, s0.y, PERM_HI)), acc3, false);
        den  = __builtin_amdgcn_fdot2(ppA, one2, den, false);
        acc0 = __builtin_amdgcn_fdot2(ppB, u2h2(__builtin_amdgcn_perm(s3.x, s2.x, PERM_LO)), acc0, false);
        acc1 = __builtin_amdgcn_fdot2(ppB, u2h2(__builtin_amdgcn_perm(s3.x, s2.x, PERM_HI)), acc1, false);
        acc2 = __builtin_amdgcn_fdot2(ppB, u2h2(__builtin_amdgcn_perm(s3.y, s2.y, PERM_LO)), acc2, false);
        acc3 = __builtin_amdgcn_fdot2(ppB, u2h2(__builtin_amdgcn_perm(s3.y, s2.y, PERM_HI)), acc3, false);
        den  = __builtin_amdgcn_fdot2(ppB, one2, den, false);
    }
    if (t + 2 <= end) {
        const unsigned long long q0 = pd[t], q1 = pd[t + 1];
        const int d0 = (int)(q0 >> 32), d1 = (int)(q1 >> 32);
        const uint2 s0 = *(const uint2*)(seql + (size_t)d0 * FOUT);
        const uint2 s1 = *(const uint2*)(seql + (size_t)d1 * FOUT);
        const h16x2 ppA = u2h2(((uint32_t)q0 & 0xffffu) | ((uint32_t)q1 << 16));
        acc0 = __builtin_amdgcn_fdot2(ppA, u2h2(__builtin_amdgcn_perm(s1.x, s0.x, PERM_LO)), acc0, false);
        acc1 = __builtin_amdgcn_fdot2(ppA, u2h2(__builtin_amdgcn_perm(s1.x, s0.x, PERM_HI)), acc1, false);
        acc2 = __builtin_amdgcn_fdot2(ppA, u2h2(__builtin_amdgcn_perm(s1.y, s0.y, PERM_LO)), acc2, false);
        acc3 = __builtin_amdgcn_fdot2(ppA, u2h2(__builtin_amdgcn_perm(s1.y, s0.y, PERM_HI)), acc3, false);
        den  = __builtin_amdgcn_fdot2(ppA, one2, den, false);
        t += 2;
    }
    if (t < end) {
        const unsigned long long q0 = pd[t];
        const int d0 = (int)(q0 >> 32);
        const uint2 s0 = *(const uint2*)(seql + (size_t)d0 * FOUT);
        const h16x2 ppA = u2h2((uint32_t)q0 & 0xffffu);   // hi half = 0 -> pairs contribute 0
        acc0 = __builtin_amdgcn_fdot2(ppA, u2h2(__builtin_amdgcn_perm(s0.x, s0.x, PERM_LO)), acc0, false);
        acc1 = __builtin_amdgcn_fdot2(ppA, u2h2(__builtin_amdgcn_perm(s0.x, s0.x, PERM_HI)), acc1, false);
        acc2 = __builtin_amdgcn_fdot2(ppA, u2h2(__builtin_amdgcn_perm(s0.y, s0.y, PERM_LO)), acc2, false);
        acc3 = __builtin_amdgcn_fdot2(ppA, u2h2(__builtin_amdgcn_perm(s0.y, s0.y, PERM_HI)), acc3, false);
        den  = __builtin_amdgcn_fdot2(ppA, one2, den, false);
    }

    const float inv = (end > start) ? 1.f / den : 0.f;
    const float4 bo = *(const float4*)(b_out + lane * 4);
    f32x4 o;
    o[0] = acc0 * inv + bo.x;
    o[1] = acc1 * inv + bo.y;
    o[2] = acc2 * inv + bo.z;
    o[3] = acc3 * inv + bo.w;
    o[0] = (o[0] > 0.f) ? o[0] : expm1f(o[0]);
    o[1] = (o[1] > 0.f) ? o[1] : expm1f(o[1]);
    o[2] = (o[2] > 0.f) ? o[2] : expm1f(o[2]);
    o[3] = (o[3] > 0.f) ? o[3] : expm1f(o[3]);
    __builtin_nontemporal_store(o, (f32x4*)(out + (size_t)row * FOUT + lane * 4));
}

extern "C" void kernel_launch(void* const* d_in, const int* in_sizes, int n_in,
                              void* d_out, int out_size, void* d_ws, size_t ws_size,
                              hipStream_t stream)
{
    const float* x      = (const float*)d_in[0];
    const float* values = (const float*)d_in[1];
    const int*   ei     = (const int*)d_in[2];
    const float* W      = (const float*)d_in[3];
    const float* a1     = (const float*)d_in[4];
    const float* b1     = (const float*)d_in[5];
    const float* a2     = (const float*)d_in[6];
    const float* b2     = (const float*)d_in[7];
    const float* b_out  = (const float*)d_in[8];
    float* out = (float*)d_out;

    const int N = in_sizes[0] / FIN;   // 63001
    const int E = in_sizes[1];         // 2,000,000
    const int* src = ei;
    const int* dst = ei + E;
    const int K = N * NBKT;

    auto alignup = [](size_t v) { return (v + 255) & ~(size_t)255; };
    char* ws = (char*)d_ws;
    size_t off = 0;
    ushort* seqh  = (ushort*)(ws + off); off = alignup(off + (size_t)N * FOUT * 2);
    ushort* WT    = (ushort*)(ws + off); off = alignup(off + (size_t)FIN * FOUT * 2);
    float*  f1    = (float*)(ws + off);  off = alignup(off + (size_t)N * 4);
    float*  f2    = (float*)(ws + off);  off = alignup(off + (size_t)N * 4);
    int*    cnt   = (int*)(ws + off);    off = alignup(off + (size_t)K * 4);
    int*    koff  = (int*)(ws + off);    off = alignup(off + (size_t)(K + 1) * 4);
    int*    btot  = (int*)(ws + off);    off = alignup(off + (size_t)1024 * 4);
    int*    boff  = (int*)(ws + off);    off = alignup(off + (size_t)1024 * 4);
    int*    pos   = (int*)(ws + off);    off = alignup(off + (size_t)E * 4);
    unsigned long long* pd = (unsigned long long*)(ws + off); off = alignup(off + (size_t)E * 8);
    (void)ws_size;

    const int nbk = (K + 1023) / 1024;   // 493

    hipMemsetAsync(cnt, 0, (size_t)K * 4, stream);

    pos_kernel<<<(E / 4 + 255) / 256, 256, 0, stream>>>(src, dst, cnt, pos, E);
    scan_blk<<<nbk, 1024, 0, stream>>>(cnt, btot, K);
    scan_top<<<1, 1024, 0, stream>>>(btot, boff, nbk);
    scan_out<<<nbk, 1024, 0, stream>>>(cnt, boff, koff, K);

    prep_wt<<<(FIN * FOUT + 255) / 256, 256, 0, stream>>>(W, WT);
    gemm_bf16<<<(N + BM - 1) / BM, 512, 0, stream>>>(x, WT, seqh, a1, a2, b1, b2,
                                                     f1, f2, N);

    scatter_p<<<(E + 255) / 256, 256, 0, stream>>>(src, dst, values, pos, f1, f2,
                                                   koff, pd, E);

    spmm_kernel<<<(N + 3) / 4, 256, 0, stream>>>(seqh, pd, koff, b_out, out, N);
}